// Round 6
// baseline (1516.603 us; speedup 1.0000x reference)
//
#include <hip/hip_runtime.h>
#include <hip/hip_bf16.h>

#define N_NODES 25000
#define N_EDGES 200000
#define N_GRAPHS 64
#define HID 128
#define DEPTH 5

typedef _Float16 half8 __attribute__((ext_vector_type(8)));
typedef float f32x4 __attribute__((ext_vector_type(4)));

__device__ inline half8 pack8(float4 a, float4 b) {
    half8 r;
    r[0] = (_Float16)a.x; r[1] = (_Float16)a.y; r[2] = (_Float16)a.z; r[3] = (_Float16)a.w;
    r[4] = (_Float16)b.x; r[5] = (_Float16)b.y; r[6] = (_Float16)b.z; r[7] = (_Float16)b.w;
    return r;
}

// ---------------- embed ----------------
__global__ void embed_kernel(const float* __restrict__ x, const float* __restrict__ W,
                             const float* __restrict__ b, float* __restrict__ h) {
    for (int i = blockIdx.x * blockDim.x + threadIdx.x; i < N_NODES * HID;
         i += gridDim.x * blockDim.x) {
        int n = i >> 7, j = i & 127;
        float acc = b[j];
        #pragma unroll
        for (int k = 0; k < 16; k++) acc += x[n * 16 + k] * W[k * 128 + j];
        h[i] = acc;
    }
}

// ---------------- weight prep: f32 -> f16 in MFMA B-fragment layout ----------------
// arena[((kb*8+t)*64+lane)*8+j] = W[kb*32+(lane>>4)*8+j][(lane&15)*8+t]
__global__ void prep_kernel(const float* __restrict__ updW1, const float* __restrict__ updW2,
                            const float* __restrict__ msgW2,
                            _Float16* __restrict__ wU1, _Float16* __restrict__ wU2,
                            _Float16* __restrict__ wE2) {
    int i = blockIdx.x * blockDim.x + threadIdx.x;
    const int T1 = DEPTH * 32768, T2 = DEPTH * 16384;
    if (i < T1) {
        int l = i >> 15, r = i & 32767;
        int j = r & 7, lane = (r >> 3) & 63, t = (r >> 9) & 7, kb = r >> 12;
        int k = kb * 32 + (lane >> 4) * 8 + j, c = (lane & 15) * 8 + t;
        wU1[i] = (_Float16)updW1[(size_t)l * 256 * 128 + k * 128 + c];
    } else if (i < T1 + T2) {
        int ii = i - T1;
        int l = ii >> 14, r = ii & 16383;
        int j = r & 7, lane = (r >> 3) & 63, t = (r >> 9) & 7, kb = r >> 12;
        int k = kb * 32 + (lane >> 4) * 8 + j, c = (lane & 15) * 8 + t;
        wU2[ii] = (_Float16)updW2[(size_t)l * 128 * 128 + k * 128 + c];
    } else if (i < T1 + 2 * T2) {
        int ii = i - T1 - T2;
        int l = ii >> 14, r = ii & 16383;
        int j = r & 7, lane = (r >> 3) & 63, t = (r >> 9) & 7, kb = r >> 12;
        int k = kb * 32 + (lane >> 4) * 8 + j, c = (lane & 15) * 8 + t;
        wE2[ii] = (_Float16)msgW2[(size_t)l * 128 * 128 + k * 128 + c];
    }
}

// ---------------- CSR build ----------------
__global__ void hist_kernel(const int* __restrict__ ei, int* __restrict__ cnt) {
    int e = blockIdx.x * blockDim.x + threadIdx.x;
    if (e < N_EDGES) atomicAdd(&cnt[ei[N_EDGES + e]], 1);
}

__global__ __launch_bounds__(1024)
void scan_kernel(const int* cnt, int* rowptr, int* cursor) {   // cnt may alias cursor
    __shared__ int swsum[16];
    __shared__ int stot;
    const int tid = threadIdx.x, wave = tid >> 6, lane = tid & 63;
    int carry = 0;
    for (int base = 0; base < N_NODES; base += 1024) {
        int i = base + tid;
        int v0 = (i < N_NODES) ? cnt[i] : 0;
        int v = v0;
        #pragma unroll
        for (int d = 1; d < 64; d <<= 1) {
            int t = __shfl_up(v, d, 64);
            if (lane >= d) v += t;
        }
        if (lane == 63) swsum[wave] = v;
        __syncthreads();
        if (wave == 0) {
            int sv = (lane < 16) ? swsum[lane] : 0;
            int si = sv;
            #pragma unroll
            for (int d = 1; d < 16; d <<= 1) {
                int t = __shfl_up(si, d, 64);
                if (lane >= d) si += t;
            }
            if (lane < 16) swsum[lane] = si - sv;
            if (lane == 15) stot = si;
        }
        __syncthreads();
        int excl = v - v0 + swsum[wave] + carry;
        if (i < N_NODES) { rowptr[i] = excl; cursor[i] = excl; }
        carry += stot;
        __syncthreads();
    }
    if (tid == 0) rowptr[N_NODES] = carry;
}

__global__ void scatter_kernel(const int* __restrict__ ei, const float* __restrict__ pos,
                               int* __restrict__ cursor, int* __restrict__ src_s,
                               int* __restrict__ dst_s, _Float16* __restrict__ dist_s) {
    int e = blockIdx.x * blockDim.x + threadIdx.x;
    if (e < N_EDGES) {
        int s = ei[e], d = ei[N_EDGES + e];
        int p = atomicAdd(&cursor[d], 1);
        src_s[p] = s; dst_s[p] = d;
        float dx = pos[d * 3 + 0] - pos[s * 3 + 0];
        float dy = pos[d * 3 + 1] - pos[s * 3 + 1];
        float dz = pos[d * 3 + 2] - pos[s * 3 + 2];
        dist_s[p] = (_Float16)sqrtf(dx * dx + dy * dy + dz * dz);
    }
}

// ---------------- US precompute (LDS-staged weights; runs fine at 2 blk/CU) ----------------
__global__ __launch_bounds__(512, 2)
void us_kernel(const float* __restrict__ h, const float* __restrict__ W1,
               const float* __restrict__ bias1,
               _Float16* __restrict__ U, _Float16* __restrict__ S) {
    __shared__ _Float16 sW[32768];   // [kb(4)][tt(16)][lane(64)][j(8)]
    __shared__ float sB1[128];
    const int tid = threadIdx.x;
    for (int idx = tid; idx < 128 * 256; idx += 512) {
        int kk = idx >> 8, c = idx & 255;
        int cc = c & 127, s_ = cc >> 3, tt = (cc & 7) + ((c >> 7) << 3);
        float val = (c < 128) ? W1[kk * 128 + c] : W1[(128 + kk) * 128 + (c - 128)];
        int kb = kk >> 5, kq = (kk >> 3) & 3, j = kk & 7;
        sW[((((kb << 4) + tt) << 6) + ((kq << 4) | s_)) * 8 + j] = (_Float16)val;
    }
    if (tid < 128) sB1[tid] = bias1[tid];
    __syncthreads();

    const int w = tid >> 6, lane = tid & 63, quad = lane >> 4, s = lane & 15;
    float b1c[8];
    #pragma unroll
    for (int t = 0; t < 8; t++) b1c[t] = sB1[s * 8 + t];

    const int gw = blockIdx.x * 8 + w, nwaves = gridDim.x * 8;
    const int nwt = (N_NODES + 15) >> 4;
    for (int wt = gw; wt < nwt; wt += nwaves) {
        const int nbase = wt << 4;
        int n = nbase + s; if (n >= N_NODES) n = N_NODES - 1;
        f32x4 acc[16];
        #pragma unroll
        for (int tt = 0; tt < 16; tt++) { f32x4 z = {0.f, 0.f, 0.f, 0.f}; acc[tt] = z; }
        #pragma unroll
        for (int kb = 0; kb < 4; kb++) {
            const float* rp = h + (size_t)n * 128 + kb * 32 + quad * 8;
            half8 af = pack8(*(const float4*)rp, *(const float4*)(rp + 4));
            #pragma unroll
            for (int tt = 0; tt < 16; tt++) {
                half8 bf = *(const half8*)(&sW[((((kb << 4) + tt) << 6) + lane) * 8]);
                acc[tt] = __builtin_amdgcn_mfma_f32_16x16x32_f16(af, bf, acc[tt], 0, 0, 0);
            }
        }
        #pragma unroll
        for (int r = 0; r < 4; r++) {
            int nn = nbase + quad * 4 + r;
            if (nn < N_NODES) {
                half8 uv, sv;
                #pragma unroll
                for (int t = 0; t < 8; t++) {
                    uv[t] = (_Float16)(acc[t][r] + b1c[t]);
                    sv[t] = (_Float16)(acc[t + 8][r]);
                }
                *(half8*)(&U[(size_t)nn * 128 + s * 8]) = uv;
                *(half8*)(&S[(size_t)nn * 128 + s * 8]) = sv;
            }
        }
    }
}

// ---------------- edge kernel: B-operand from global f16 arena ----------------
__global__ __launch_bounds__(256, 3)
void edge_kernel(const _Float16* __restrict__ U, const _Float16* __restrict__ S,
                 const _Float16* __restrict__ dist_s, const int* __restrict__ src_s,
                 const int* __restrict__ dst_s,
                 const float* __restrict__ w256, const float* __restrict__ gam1,
                 const float* __restrict__ bet1,
                 const _Float16* __restrict__ W2f, const float* __restrict__ bias2,
                 const float* __restrict__ gam2, const float* __restrict__ bet2,
                 _Float16* __restrict__ m2) {
    __shared__ _Float16 sM1[17408];   // 4 waves x [32 rows][136]
    __shared__ float sB[768];

    const int tid = threadIdx.x;
    if (tid < 128) {
        sB[tid] = w256[tid];
        sB[128 + tid] = gam1[tid]; sB[256 + tid] = bet1[tid];
        sB[384 + tid] = bias2[tid]; sB[512 + tid] = gam2[tid]; sB[640 + tid] = bet2[tid];
    }
    __syncthreads();

    const int w = tid >> 6, lane = tid & 63, quad = lane >> 4, s = lane & 15;
    _Float16* myM1 = &sM1[w * (32 * 136)];
    const half8* B2 = (const half8*)W2f;

    float w256c[8], g1c[8], be1c[8], b2c[8], g2c[8], be2c[8];
    #pragma unroll
    for (int t = 0; t < 8; t++) {
        int c = s * 8 + t;
        w256c[t] = sB[c]; g1c[t] = sB[128 + c]; be1c[t] = sB[256 + c];
        b2c[t] = sB[384 + c]; g2c[t] = sB[512 + c]; be2c[t] = sB[640 + c];
    }

    const int gw = blockIdx.x * 4 + w, nwaves = gridDim.x * 4;
    const int ewt = (N_EDGES + 31) >> 5;
    for (int wt = gw; wt < ewt; wt += nwaves) {
        const int ebase = wt << 5;

        // phase A: gather (max outstanding loads)
        float distA[8];
        half8 u8A[8], s8A[8];
        int dA[8], siA[8];
        #pragma unroll
        for (int i = 0; i < 8; i++) {
            int e = ebase + (i >> 2) * 16 + quad * 4 + (i & 3);
            int ec = (e >= N_EDGES) ? (N_EDGES - 1) : e;
            dA[i] = dst_s[ec]; siA[i] = src_s[ec]; distA[i] = (float)dist_s[ec];
        }
        #pragma unroll
        for (int i = 0; i < 8; i++) {
            u8A[i] = *(const half8*)(&U[(size_t)dA[i] * 128 + s * 8]);
            s8A[i] = *(const half8*)(&S[(size_t)siA[i] * 128 + s * 8]);
        }

        // phase B: LN + relu -> myM1 (per-wave; in-order DS pipe, no barrier)
        #pragma unroll
        for (int i = 0; i < 8; i++) {
            float v[8], sum = 0.f, sq = 0.f;
            #pragma unroll
            for (int t = 0; t < 8; t++) {
                v[t] = (float)u8A[i][t] + (float)s8A[i][t] + distA[i] * w256c[t];
                sum += v[t]; sq += v[t] * v[t];
            }
            #pragma unroll
            for (int m = 1; m < 16; m <<= 1) {
                sum += __shfl_xor(sum, m, 64);
                sq  += __shfl_xor(sq, m, 64);
            }
            float mean = sum * (1.f / 128.f);
            float var = sq * (1.f / 128.f) - mean * mean;
            float rstd = rsqrtf(var + 1e-5f);
            half8 hv;
            #pragma unroll
            for (int t = 0; t < 8; t++) {
                float y = (v[t] - mean) * rstd * g1c[t] + be1c[t];
                hv[t] = (_Float16)fmaxf(y, 0.f);
            }
            *(half8*)(&myM1[((i >> 2) * 16 + quad * 4 + (i & 3)) * 136 + s * 8]) = hv;
        }

        // GEMM2 (B from global arena, L2-hot broadcast)
        f32x4 acc2[2][8];
        #pragma unroll
        for (int mt = 0; mt < 2; mt++)
            #pragma unroll
            for (int t = 0; t < 8; t++) { f32x4 z = {0.f, 0.f, 0.f, 0.f}; acc2[mt][t] = z; }
        #pragma unroll
        for (int kb = 0; kb < 4; kb++) {
            half8 af[2];
            #pragma unroll
            for (int mt = 0; mt < 2; mt++)
                af[mt] = *(const half8*)(&myM1[(mt * 16 + s) * 136 + kb * 32 + quad * 8]);
            #pragma unroll
            for (int t = 0; t < 8; t++) {
                half8 bf = B2[((kb << 3) + t) * 64 + lane];
                acc2[0][t] = __builtin_amdgcn_mfma_f32_16x16x32_f16(af[0], bf, acc2[0][t], 0, 0, 0);
                acc2[1][t] = __builtin_amdgcn_mfma_f32_16x16x32_f16(af[1], bf, acc2[1][t], 0, 0, 0);
            }
        }

        // epilogue 2: LN ; relu ; store m2
        #pragma unroll
        for (int mt = 0; mt < 2; mt++) {
            #pragma unroll
            for (int r = 0; r < 4; r++) {
                int e = ebase + mt * 16 + quad * 4 + r;
                float v[8], sum = 0.f, sq = 0.f;
                #pragma unroll
                for (int t = 0; t < 8; t++) {
                    v[t] = acc2[mt][t][r] + b2c[t];
                    sum += v[t]; sq += v[t] * v[t];
                }
                #pragma unroll
                for (int m = 1; m < 16; m <<= 1) {
                    sum += __shfl_xor(sum, m, 64);
                    sq  += __shfl_xor(sq, m, 64);
                }
                float mean = sum * (1.f / 128.f);
                float var = sq * (1.f / 128.f) - mean * mean;
                float rstd = rsqrtf(var + 1e-5f);
                if (e < N_EDGES) {
                    half8 hv;
                    #pragma unroll
                    for (int t = 0; t < 8; t++) {
                        float y = (v[t] - mean) * rstd * g2c[t] + be2c[t];
                        hv[t] = (_Float16)fmaxf(y, 0.f);
                    }
                    *(half8*)(&m2[(size_t)e * 128 + s * 8]) = hv;
                }
            }
        }
    }
}

// ---------------- upd: fused agg + node-MLP + residual (global-B, 256 thr) ----------------
__global__ __launch_bounds__(256, 4)
void upd_kernel(float* __restrict__ h, const _Float16* __restrict__ m2,
                const int* __restrict__ rowptr,
                const _Float16* __restrict__ W1f, const float* __restrict__ bias1,
                const float* __restrict__ gam1, const float* __restrict__ bet1,
                const _Float16* __restrict__ W2f, const float* __restrict__ bias2,
                const float* __restrict__ gam2, const float* __restrict__ bet2) {
    __shared__ _Float16 sM1[8704];    // 4 waves x [16 rows][136]
    __shared__ float sB[768];

    const int tid = threadIdx.x;
    if (tid < 128) {
        sB[tid] = bias1[tid]; sB[128 + tid] = gam1[tid]; sB[256 + tid] = bet1[tid];
        sB[384 + tid] = bias2[tid]; sB[512 + tid] = gam2[tid]; sB[640 + tid] = bet2[tid];
    }
    __syncthreads();

    const int w = tid >> 6, lane = tid & 63, quad = lane >> 4, s = lane & 15;
    _Float16* myM1 = &sM1[w * (16 * 136)];
    const half8* B1 = (const half8*)W1f;
    const half8* B2 = (const half8*)W2f;

    float b1c[8], g1c[8], be1c[8], b2c[8], g2c[8], be2c[8];
    #pragma unroll
    for (int t = 0; t < 8; t++) {
        int c = s * 8 + t;
        b1c[t] = sB[c]; g1c[t] = sB[128 + c]; be1c[t] = sB[256 + c];
        b2c[t] = sB[384 + c]; g2c[t] = sB[512 + c]; be2c[t] = sB[640 + c];
    }

    const int gw = blockIdx.x * 4 + w, nwaves = gridDim.x * 4;
    const int nwt = (N_NODES + 15) >> 4;
    for (int wt = gw; wt < nwt; wt += nwaves) {
        const int nbase = wt << 4;
        int n = nbase + s; if (n >= N_NODES) n = N_NODES - 1;

        // phase 0: agg (f16 packed accumulate, unroll-2) -> myM1
        {
            int lo = rowptr[n], hi = rowptr[n + 1];
            half8 a[4];
            #pragma unroll
            for (int c = 0; c < 4; c++)
                #pragma unroll
                for (int j = 0; j < 8; j++) a[c][j] = (_Float16)0.f;
            int r = lo;
            for (; r + 2 <= hi; r += 2) {
                const half8* p0 = (const half8*)(m2 + (size_t)r * 128 + quad * 32);
                const half8* p1 = (const half8*)(m2 + (size_t)(r + 1) * 128 + quad * 32);
                half8 x0 = p0[0], x1 = p0[1], x2 = p0[2], x3 = p0[3];
                half8 y0 = p1[0], y1 = p1[1], y2 = p1[2], y3 = p1[3];
                a[0] += x0 + y0; a[1] += x1 + y1; a[2] += x2 + y2; a[3] += x3 + y3;
            }
            if (r < hi) {
                const half8* p0 = (const half8*)(m2 + (size_t)r * 128 + quad * 32);
                a[0] += p0[0]; a[1] += p0[1]; a[2] += p0[2]; a[3] += p0[3];
            }
            #pragma unroll
            for (int c = 0; c < 4; c++)
                *(half8*)(&myM1[s * 136 + quad * 32 + c * 8]) = a[c];
        }
        // per-wave LDS, in-order DS pipe -> no barrier needed

        // GEMM1: A = [h[n] | agg]
        f32x4 acc[8];
        #pragma unroll
        for (int t = 0; t < 8; t++) { f32x4 z = {0.f, 0.f, 0.f, 0.f}; acc[t] = z; }
        #pragma unroll
        for (int kb = 0; kb < 8; kb++) {
            half8 af;
            if (kb < 4) {
                const float* rp = h + (size_t)n * 128 + kb * 32 + quad * 8;
                af = pack8(*(const float4*)rp, *(const float4*)(rp + 4));
            } else {
                af = *(const half8*)(&myM1[s * 136 + (kb - 4) * 32 + quad * 8]);
            }
            #pragma unroll
            for (int t = 0; t < 8; t++) {
                half8 bf = B1[((kb << 3) + t) * 64 + lane];
                acc[t] = __builtin_amdgcn_mfma_f32_16x16x32_f16(af, bf, acc[t], 0, 0, 0);
            }
        }

        // epilogue 1: LN ; relu ; -> myM1
        #pragma unroll
        for (int r = 0; r < 4; r++) {
            float v[8], sum = 0.f, sq = 0.f;
            #pragma unroll
            for (int t = 0; t < 8; t++) {
                v[t] = acc[t][r] + b1c[t];
                sum += v[t]; sq += v[t] * v[t];
            }
            #pragma unroll
            for (int m = 1; m < 16; m <<= 1) {
                sum += __shfl_xor(sum, m, 64);
                sq  += __shfl_xor(sq, m, 64);
            }
            float mean = sum * (1.f / 128.f);
            float var = sq * (1.f / 128.f) - mean * mean;
            float rstd = rsqrtf(var + 1e-5f);
            half8 hv;
            #pragma unroll
            for (int t = 0; t < 8; t++) {
                float y = (v[t] - mean) * rstd * g1c[t] + be1c[t];
                hv[t] = (_Float16)fmaxf(y, 0.f);
            }
            *(half8*)(&myM1[(quad * 4 + r) * 136 + s * 8]) = hv;
        }

        // GEMM2
        f32x4 acc2[8];
        #pragma unroll
        for (int t = 0; t < 8; t++) { f32x4 z = {0.f, 0.f, 0.f, 0.f}; acc2[t] = z; }
        #pragma unroll
        for (int kb = 0; kb < 4; kb++) {
            half8 af = *(const half8*)(&myM1[s * 136 + kb * 32 + quad * 8]);
            #pragma unroll
            for (int t = 0; t < 8; t++) {
                half8 bf = B2[((kb << 3) + t) * 64 + lane];
                acc2[t] = __builtin_amdgcn_mfma_f32_16x16x32_f16(af, bf, acc2[t], 0, 0, 0);
            }
        }

        // epilogue 2: LN ; relu ; h += u
        #pragma unroll
        for (int r = 0; r < 4; r++) {
            int nn = nbase + quad * 4 + r;
            float v[8], sum = 0.f, sq = 0.f;
            #pragma unroll
            for (int t = 0; t < 8; t++) {
                v[t] = acc2[t][r] + b2c[t];
                sum += v[t]; sq += v[t] * v[t];
            }
            #pragma unroll
            for (int m = 1; m < 16; m <<= 1) {
                sum += __shfl_xor(sum, m, 64);
                sq  += __shfl_xor(sq, m, 64);
            }
            float mean = sum * (1.f / 128.f);
            float var = sq * (1.f / 128.f) - mean * mean;
            float rstd = rsqrtf(var + 1e-5f);
            if (nn < N_NODES) {
                float* hp = h + (size_t)nn * 128 + s * 8;
                float4 h0 = *(float4*)hp;
                float4 h1 = *(float4*)(hp + 4);
                float y[8];
                #pragma unroll
                for (int t = 0; t < 8; t++) {
                    float u = (v[t] - mean) * rstd * g2c[t] + be2c[t];
                    y[t] = fmaxf(u, 0.f);
                }
                h0.x += y[0]; h0.y += y[1]; h0.z += y[2]; h0.w += y[3];
                h1.x += y[4]; h1.y += y[5]; h1.z += y[6]; h1.w += y[7];
                *(float4*)hp = h0;
                *(float4*)(hp + 4) = h1;
            }
        }
    }
}

// ---------------- pool (parallel, segmented + atomics) ----------------
__global__ void pool_kernel(const float* __restrict__ h, const int* __restrict__ batch,
                            float* __restrict__ g) {
    const int CHUNK = 125;
    int blo = blockIdx.x * CHUNK;
    int bhi = blo + CHUNK; if (bhi > N_NODES) bhi = N_NODES;
    int j = threadIdx.x & 127;
    int half = threadIdx.x >> 7;
    float acc = 0.f; int cur = -1;
    for (int n = blo + half; n < bhi; n += 2) {
        int b = batch[n];
        if (b != cur) {
            if (cur >= 0) atomicAdd(&g[cur * 128 + j], acc);
            cur = b; acc = 0.f;
        }
        acc += h[(size_t)n * 128 + j];
    }
    if (cur >= 0) atomicAdd(&g[cur * 128 + j], acc);
}

// ---------------- pred ----------------
__global__ void pred_kernel(const float* __restrict__ g, const float* __restrict__ W1,
                            const float* __restrict__ b1, const float* __restrict__ W2,
                            const float* __restrict__ b2, float* __restrict__ out) {
    int b = blockIdx.x, j = threadIdx.x;
    float t = b1[j];
    for (int k = 0; k < 128; k++) t += g[b * 128 + k] * W1[k * 128 + j];
    t = fmaxf(t, 0.f);
    __shared__ float red[128];
    red[j] = t * W2[j];
    __syncthreads();
    for (int off = 64; off > 0; off >>= 1) {
        if (j < off) red[j] += red[j + off];
        __syncthreads();
    }
    if (j == 0) out[b] = red[0] + b2[0];
}

extern "C" void kernel_launch(void* const* d_in, const int* in_sizes, int n_in,
                              void* d_out, int out_size, void* d_ws, size_t ws_size,
                              hipStream_t stream) {
    const float* x      = (const float*)d_in[0];
    const float* pos    = (const float*)d_in[1];
    const int*   ei     = (const int*)d_in[2];
    const int*   batch  = (const int*)d_in[3];
    const float* emb_W  = (const float*)d_in[4];
    const float* emb_b  = (const float*)d_in[5];
    const float* msg_W1 = (const float*)d_in[6];
    const float* msg_b1 = (const float*)d_in[7];
    const float* msg_W2 = (const float*)d_in[8];
    const float* msg_b2 = (const float*)d_in[9];
    const float* upd_W1 = (const float*)d_in[10];
    const float* upd_b1 = (const float*)d_in[11];
    const float* upd_W2 = (const float*)d_in[12];
    const float* upd_b2 = (const float*)d_in[13];
    const float* msg_g1 = (const float*)d_in[14];
    const float* msg_be1= (const float*)d_in[15];
    const float* msg_g2 = (const float*)d_in[16];
    const float* msg_be2= (const float*)d_in[17];
    const float* upd_g1 = (const float*)d_in[18];
    const float* upd_be1= (const float*)d_in[19];
    const float* upd_g2 = (const float*)d_in[20];
    const float* upd_be2= (const float*)d_in[21];
    const float* pred_W1= (const float*)d_in[22];
    const float* pred_b1= (const float*)d_in[23];
    const float* pred_W2= (const float*)d_in[24];
    const float* pred_b2= (const float*)d_in[25];
    float* out = (float*)d_out;

    float* ws = (float*)d_ws;
    float*     h      = ws;                           // 3.2M floats
    _Float16*  U      = (_Float16*)(ws + 3200000);    // 3.2M halves
    _Float16*  S      = (_Float16*)(ws + 4800000);    // 3.2M halves
    _Float16*  m2     = (_Float16*)(ws + 6400000);    // 25.6M halves
    int*       rowptr = (int*)(ws + 19200000);        // 25,008
    int*       cursor = rowptr + 25008;               // 25,008 (doubles as cnt)
    int*       src_s  = cursor + 25008;               // 200,000
    int*       dst_s  = src_s + 200000;               // 200,000
    _Float16*  dist_s = (_Float16*)(dst_s + 200000);  // 200,000 halves (100,000 slots)
    float*     g      = (float*)(dist_s + 200000);    // 8,192
    _Float16*  wU1    = (_Float16*)(g + 8192);        // 5 x 32768 halves
    _Float16*  wU2    = wU1 + DEPTH * 32768;          // 5 x 16384
    _Float16*  wE2    = wU2 + DEPTH * 16384;          // 5 x 16384

    hipMemsetAsync(cursor, 0, 25001 * sizeof(int), stream);
    hist_kernel<<<(N_EDGES + 255) / 256, 256, 0, stream>>>(ei, cursor);
    scan_kernel<<<1, 1024, 0, stream>>>(cursor, rowptr, cursor);
    scatter_kernel<<<(N_EDGES + 255) / 256, 256, 0, stream>>>(ei, pos, cursor, src_s, dst_s, dist_s);
    prep_kernel<<<1280, 256, 0, stream>>>(upd_W1, upd_W2, msg_W2, wU1, wU2, wE2);

    embed_kernel<<<4096, 256, 0, stream>>>(x, emb_W, emb_b, h);

    for (int l = 0; l < DEPTH; l++) {
        const float* W1l = msg_W1 + (size_t)l * 257 * 128;
        us_kernel<<<256, 512, 0, stream>>>(h, W1l, msg_b1 + l * 128, U, S);
        edge_kernel<<<512, 256, 0, stream>>>(
            U, S, dist_s, src_s, dst_s,
            W1l + 256 * 128, msg_g1 + l * 128, msg_be1 + l * 128,
            wE2 + (size_t)l * 16384, msg_b2 + l * 128, msg_g2 + l * 128, msg_be2 + l * 128,
            m2);
        upd_kernel<<<392, 256, 0, stream>>>(
            h, m2, rowptr,
            wU1 + (size_t)l * 32768, upd_b1 + l * 128, upd_g1 + l * 128, upd_be1 + l * 128,
            wU2 + (size_t)l * 16384, upd_b2 + l * 128, upd_g2 + l * 128, upd_be2 + l * 128);
    }

    hipMemsetAsync(g, 0, N_GRAPHS * 128 * sizeof(float), stream);
    pool_kernel<<<200, 256, 0, stream>>>(h, batch, g);
    pred_kernel<<<64, 128, 0, stream>>>(g, pred_W1, pred_b1, pred_W2, pred_b2, out);
}

// Round 7
// 1101.299 us; speedup vs baseline: 1.3771x; 1.3771x over previous
//
#include <hip/hip_runtime.h>
#include <hip/hip_bf16.h>

#define N_NODES 25000
#define N_EDGES 200000
#define N_GRAPHS 64
#define HID 128
#define DEPTH 5

typedef _Float16 half8 __attribute__((ext_vector_type(8)));
typedef float f32x4 __attribute__((ext_vector_type(4)));

__device__ inline half8 pack8(float4 a, float4 b) {
    half8 r;
    r[0] = (_Float16)a.x; r[1] = (_Float16)a.y; r[2] = (_Float16)a.z; r[3] = (_Float16)a.w;
    r[4] = (_Float16)b.x; r[5] = (_Float16)b.y; r[6] = (_Float16)b.z; r[7] = (_Float16)b.w;
    return r;
}

// ---------------- embed ----------------
__global__ void embed_kernel(const float* __restrict__ x, const float* __restrict__ W,
                             const float* __restrict__ b, float* __restrict__ h) {
    for (int i = blockIdx.x * blockDim.x + threadIdx.x; i < N_NODES * HID;
         i += gridDim.x * blockDim.x) {
        int n = i >> 7, j = i & 127;
        float acc = b[j];
        #pragma unroll
        for (int k = 0; k < 16; k++) acc += x[n * 16 + k] * W[k * 128 + j];
        h[i] = acc;
    }
}

// ---------------- CSR build ----------------
__global__ void hist_kernel(const int* __restrict__ ei, int* __restrict__ cnt) {
    int e = blockIdx.x * blockDim.x + threadIdx.x;
    if (e < N_EDGES) atomicAdd(&cnt[ei[N_EDGES + e]], 1);
}

__global__ __launch_bounds__(1024)
void scan_kernel(const int* cnt, int* rowptr, int* cursor) {   // cnt may alias cursor
    __shared__ int swsum[16];
    __shared__ int stot;
    const int tid = threadIdx.x, wave = tid >> 6, lane = tid & 63;
    int carry = 0;
    for (int base = 0; base < N_NODES; base += 1024) {
        int i = base + tid;
        int v0 = (i < N_NODES) ? cnt[i] : 0;
        int v = v0;
        #pragma unroll
        for (int d = 1; d < 64; d <<= 1) {
            int t = __shfl_up(v, d, 64);
            if (lane >= d) v += t;
        }
        if (lane == 63) swsum[wave] = v;
        __syncthreads();
        if (wave == 0) {
            int sv = (lane < 16) ? swsum[lane] : 0;
            int si = sv;
            #pragma unroll
            for (int d = 1; d < 16; d <<= 1) {
                int t = __shfl_up(si, d, 64);
                if (lane >= d) si += t;
            }
            if (lane < 16) swsum[lane] = si - sv;
            if (lane == 15) stot = si;
        }
        __syncthreads();
        int excl = v - v0 + swsum[wave] + carry;
        if (i < N_NODES) { rowptr[i] = excl; cursor[i] = excl; }
        carry += stot;
        __syncthreads();
    }
    if (tid == 0) rowptr[N_NODES] = carry;
}

__global__ void scatter_kernel(const int* __restrict__ ei, const float* __restrict__ pos,
                               int* __restrict__ cursor, int* __restrict__ src_s,
                               int* __restrict__ dst_s, float* __restrict__ dist_s) {
    int e = blockIdx.x * blockDim.x + threadIdx.x;
    if (e < N_EDGES) {
        int s = ei[e], d = ei[N_EDGES + e];
        int p = atomicAdd(&cursor[d], 1);
        src_s[p] = s; dst_s[p] = d;
        float dx = pos[d * 3 + 0] - pos[s * 3 + 0];
        float dy = pos[d * 3 + 1] - pos[s * 3 + 1];
        float dz = pos[d * 3 + 2] - pos[s * 3 + 2];
        dist_s[p] = sqrtf(dx * dx + dy * dy + dz * dz);
    }
}

// ---------------- US precompute ----------------
__global__ __launch_bounds__(512, 2)
void us_kernel(const float* __restrict__ h, const float* __restrict__ W1,
               const float* __restrict__ bias1,
               _Float16* __restrict__ U, _Float16* __restrict__ S) {
    __shared__ _Float16 sW[32768];   // [kb(4)][tt(16)][lane(64)][j(8)]
    __shared__ float sB1[128];
    const int tid = threadIdx.x;
    for (int idx = tid; idx < 128 * 256; idx += 512) {
        int kk = idx >> 8, c = idx & 255;
        int cc = c & 127, s_ = cc >> 3, tt = (cc & 7) + ((c >> 7) << 3);
        float val = (c < 128) ? W1[kk * 128 + c] : W1[(128 + kk) * 128 + (c - 128)];
        int kb = kk >> 5, kq = (kk >> 3) & 3, j = kk & 7;
        sW[((((kb << 4) + tt) << 6) + ((kq << 4) | s_)) * 8 + j] = (_Float16)val;
    }
    if (tid < 128) sB1[tid] = bias1[tid];
    __syncthreads();

    const int w = tid >> 6, lane = tid & 63, quad = lane >> 4, s = lane & 15;
    float b1c[8];
    #pragma unroll
    for (int t = 0; t < 8; t++) b1c[t] = sB1[s * 8 + t];

    const int gw = blockIdx.x * 8 + w, nwaves = gridDim.x * 8;
    const int nwt = (N_NODES + 15) >> 4;
    for (int wt = gw; wt < nwt; wt += nwaves) {
        const int nbase = wt << 4;
        int n = nbase + s; if (n >= N_NODES) n = N_NODES - 1;
        f32x4 acc[16];
        #pragma unroll
        for (int tt = 0; tt < 16; tt++) { f32x4 z = {0.f, 0.f, 0.f, 0.f}; acc[tt] = z; }
        #pragma unroll
        for (int kb = 0; kb < 4; kb++) {
            const float* rp = h + (size_t)n * 128 + kb * 32 + quad * 8;
            half8 af = pack8(*(const float4*)rp, *(const float4*)(rp + 4));
            #pragma unroll
            for (int tt = 0; tt < 16; tt++) {
                half8 bf = *(const half8*)(&sW[((((kb << 4) + tt) << 6) + lane) * 8]);
                acc[tt] = __builtin_amdgcn_mfma_f32_16x16x32_f16(af, bf, acc[tt], 0, 0, 0);
            }
        }
        #pragma unroll
        for (int r = 0; r < 4; r++) {
            int nn = nbase + quad * 4 + r;
            if (nn < N_NODES) {
                half8 uv, sv;
                #pragma unroll
                for (int t = 0; t < 8; t++) {
                    uv[t] = (_Float16)(acc[t][r] + b1c[t]);
                    sv[t] = (_Float16)(acc[t + 8][r]);
                }
                *(half8*)(&U[(size_t)nn * 128 + s * 8]) = uv;
                *(half8*)(&S[(size_t)nn * 128 + s * 8]) = sv;
            }
        }
    }
}

// ---------------- edge kernel: MLP + run-segmented atomic scatter into agg ----------------
__global__ __launch_bounds__(256, 2)
void edge_kernel(const _Float16* __restrict__ U, const _Float16* __restrict__ S,
                 const float* __restrict__ dist_s, const int* __restrict__ src_s,
                 const int* __restrict__ dst_s,
                 const float* __restrict__ w256, const float* __restrict__ gam1,
                 const float* __restrict__ bet1,
                 const float* __restrict__ W2, const float* __restrict__ bias2,
                 const float* __restrict__ gam2, const float* __restrict__ bet2,
                 float* __restrict__ agg) {
    __shared__ _Float16 sW2[16384];   // [kb(4)][t(8)][lane(64)][j(8)]
    __shared__ _Float16 sM1[17408];   // 4 waves x [32 rows][136]
    __shared__ float sB[768];

    const int tid = threadIdx.x;
    for (int idx = tid; idx < 128 * 128; idx += 256) {
        int k = idx >> 7, c = idx & 127;
        int s_ = c >> 3, t = c & 7, kb = k >> 5, kq = (k >> 3) & 3, j = k & 7;
        sW2[((((kb << 3) + t) << 6) + ((kq << 4) | s_)) * 8 + j] = (_Float16)W2[idx];
    }
    if (tid < 128) {
        sB[tid] = w256[tid];
        sB[128 + tid] = gam1[tid]; sB[256 + tid] = bet1[tid];
        sB[384 + tid] = bias2[tid]; sB[512 + tid] = gam2[tid]; sB[640 + tid] = bet2[tid];
    }
    __syncthreads();

    const int w = tid >> 6, lane = tid & 63, quad = lane >> 4, s = lane & 15;
    _Float16* myM1 = &sM1[w * (32 * 136)];

    float w256c[8], g1c[8], be1c[8], b2c[8], g2c[8], be2c[8];
    #pragma unroll
    for (int t = 0; t < 8; t++) {
        int c = s * 8 + t;
        w256c[t] = sB[c]; g1c[t] = sB[128 + c]; be1c[t] = sB[256 + c];
        b2c[t] = sB[384 + c]; g2c[t] = sB[512 + c]; be2c[t] = sB[640 + c];
    }

    const int gw = blockIdx.x * 4 + w, nwaves = gridDim.x * 4;
    const int ewt = (N_EDGES + 31) >> 5;
    for (int wt = gw; wt < ewt; wt += nwaves) {
        const int ebase = wt << 5;

        // phase A: gather (max outstanding loads)
        float distA[8];
        half8 u8A[8], s8A[8];
        int dA[8], siA[8];
        #pragma unroll
        for (int i = 0; i < 8; i++) {
            int e = ebase + (i >> 2) * 16 + quad * 4 + (i & 3);
            int ec = (e >= N_EDGES) ? (N_EDGES - 1) : e;
            dA[i] = dst_s[ec]; siA[i] = src_s[ec]; distA[i] = dist_s[ec];
        }
        #pragma unroll
        for (int i = 0; i < 8; i++) {
            u8A[i] = *(const half8*)(&U[(size_t)dA[i] * 128 + s * 8]);
            s8A[i] = *(const half8*)(&S[(size_t)siA[i] * 128 + s * 8]);
        }

        // phase B: LN + relu -> myM1 (per-wave; in-order DS pipe, no barrier)
        #pragma unroll
        for (int i = 0; i < 8; i++) {
            float v[8], sum = 0.f, sq = 0.f;
            #pragma unroll
            for (int t = 0; t < 8; t++) {
                v[t] = (float)u8A[i][t] + (float)s8A[i][t] + distA[i] * w256c[t];
                sum += v[t]; sq += v[t] * v[t];
            }
            #pragma unroll
            for (int m = 1; m < 16; m <<= 1) {
                sum += __shfl_xor(sum, m, 64);
                sq  += __shfl_xor(sq, m, 64);
            }
            float mean = sum * (1.f / 128.f);
            float var = sq * (1.f / 128.f) - mean * mean;
            float rstd = rsqrtf(var + 1e-5f);
            half8 hv;
            #pragma unroll
            for (int t = 0; t < 8; t++) {
                float y = (v[t] - mean) * rstd * g1c[t] + be1c[t];
                hv[t] = (_Float16)fmaxf(y, 0.f);
            }
            *(half8*)(&myM1[((i >> 2) * 16 + quad * 4 + (i & 3)) * 136 + s * 8]) = hv;
        }

        // GEMM2
        f32x4 acc2[2][8];
        #pragma unroll
        for (int mt = 0; mt < 2; mt++)
            #pragma unroll
            for (int t = 0; t < 8; t++) { f32x4 z = {0.f, 0.f, 0.f, 0.f}; acc2[mt][t] = z; }
        #pragma unroll
        for (int kb = 0; kb < 4; kb++) {
            half8 af[2];
            #pragma unroll
            for (int mt = 0; mt < 2; mt++)
                af[mt] = *(const half8*)(&myM1[(mt * 16 + s) * 136 + kb * 32 + quad * 8]);
            #pragma unroll
            for (int t = 0; t < 8; t++) {
                half8 bf = *(const half8*)(&sW2[(((kb << 3) + t) * 64 + lane) * 8]);
                acc2[0][t] = __builtin_amdgcn_mfma_f32_16x16x32_f16(af[0], bf, acc2[0][t], 0, 0, 0);
                acc2[1][t] = __builtin_amdgcn_mfma_f32_16x16x32_f16(af[1], bf, acc2[1][t], 0, 0, 0);
            }
        }

        // epilogue 2: LN ; relu ; m2 rows -> myM1 (overwrite m1; GEMM2 reads done)
        #pragma unroll
        for (int mt = 0; mt < 2; mt++) {
            #pragma unroll
            for (int r = 0; r < 4; r++) {
                float v[8], sum = 0.f, sq = 0.f;
                #pragma unroll
                for (int t = 0; t < 8; t++) {
                    v[t] = acc2[mt][t][r] + b2c[t];
                    sum += v[t]; sq += v[t] * v[t];
                }
                #pragma unroll
                for (int m = 1; m < 16; m <<= 1) {
                    sum += __shfl_xor(sum, m, 64);
                    sq  += __shfl_xor(sq, m, 64);
                }
                float mean = sum * (1.f / 128.f);
                float var = sq * (1.f / 128.f) - mean * mean;
                float rstd = rsqrtf(var + 1e-5f);
                half8 hv;
                #pragma unroll
                for (int t = 0; t < 8; t++) {
                    float y = (v[t] - mean) * rstd * g2c[t] + be2c[t];
                    hv[t] = (_Float16)fmaxf(y, 0.f);
                }
                *(half8*)(&myM1[(mt * 16 + quad * 4 + r) * 136 + s * 8]) = hv;
            }
        }

        // phase C: run-segmented reduction over dst runs; lane owns cols {2*lane, 2*lane+1}
        {
            const int col2 = lane * 2;
            float a0 = 0.f, a1 = 0.f;
            int dprev = -1;
            #pragma unroll 4
            for (int row = 0; row < 32; row++) {
                int e = ebase + row;
                if (e >= N_EDGES) break;
                int d = dst_s[e];
                float v0 = (float)myM1[row * 136 + col2];
                float v1 = (float)myM1[row * 136 + col2 + 1];
                a0 += v0; a1 += v1;
                int dnext = (row < 31 && e + 1 < N_EDGES) ? dst_s[e + 1] : -2;
                if (d != dnext) {
                    if (a0 != 0.f) atomicAdd(&agg[(size_t)d * 128 + col2], a0);
                    if (a1 != 0.f) atomicAdd(&agg[(size_t)d * 128 + col2 + 1], a1);
                    a0 = 0.f; a1 = 0.f;
                }
                dprev = d;
            }
        }
    }
}

// ---------------- upd: node-MLP + residual (agg from global f32) ----------------
__global__ __launch_bounds__(512, 2)
void upd_kernel(float* __restrict__ h, const float* __restrict__ agg,
                const float* __restrict__ W1, const float* __restrict__ bias1,
                const float* __restrict__ gam1, const float* __restrict__ bet1,
                const float* __restrict__ W2, const float* __restrict__ bias2,
                const float* __restrict__ gam2, const float* __restrict__ bet2) {
    __shared__ _Float16 sW1[32768];
    __shared__ _Float16 sW2[16384];
    __shared__ _Float16 sM1[17408];   // 8 waves x [16 rows][136]
    __shared__ float sB[768];

    const int tid = threadIdx.x;
    for (int idx = tid; idx < 256 * 128; idx += 512) {
        int k = idx >> 7, c = idx & 127;
        int s_ = c >> 3, t = c & 7, kb = k >> 5, kq = (k >> 3) & 3, j = k & 7;
        sW1[((((kb << 3) + t) << 6) + ((kq << 4) | s_)) * 8 + j] = (_Float16)W1[idx];
    }
    for (int idx = tid; idx < 128 * 128; idx += 512) {
        int k = idx >> 7, c = idx & 127;
        int s_ = c >> 3, t = c & 7, kb = k >> 5, kq = (k >> 3) & 3, j = k & 7;
        sW2[((((kb << 3) + t) << 6) + ((kq << 4) | s_)) * 8 + j] = (_Float16)W2[idx];
    }
    if (tid < 128) {
        sB[tid] = bias1[tid]; sB[128 + tid] = gam1[tid]; sB[256 + tid] = bet1[tid];
        sB[384 + tid] = bias2[tid]; sB[512 + tid] = gam2[tid]; sB[640 + tid] = bet2[tid];
    }
    __syncthreads();

    const int w = tid >> 6, lane = tid & 63, quad = lane >> 4, s = lane & 15;
    _Float16* myM1 = &sM1[w * (16 * 136)];

    float b1c[8], g1c[8], be1c[8], b2c[8], g2c[8], be2c[8];
    #pragma unroll
    for (int t = 0; t < 8; t++) {
        int c = s * 8 + t;
        b1c[t] = sB[c]; g1c[t] = sB[128 + c]; be1c[t] = sB[256 + c];
        b2c[t] = sB[384 + c]; g2c[t] = sB[512 + c]; be2c[t] = sB[640 + c];
    }

    const int gw = blockIdx.x * 8 + w, nwaves = gridDim.x * 8;
    const int nwt = (N_NODES + 15) >> 4;
    for (int wt = gw; wt < nwt; wt += nwaves) {
        const int nbase = wt << 4;
        int n = nbase + s; if (n >= N_NODES) n = N_NODES - 1;

        // GEMM1: A = [h[n] | agg[n]] straight from global f32
        f32x4 acc[8];
        #pragma unroll
        for (int t = 0; t < 8; t++) { f32x4 z = {0.f, 0.f, 0.f, 0.f}; acc[t] = z; }
        #pragma unroll
        for (int kb = 0; kb < 8; kb++) {
            const float* rp = (kb < 4) ? (h + (size_t)n * 128 + kb * 32 + quad * 8)
                                       : (agg + (size_t)n * 128 + (kb - 4) * 32 + quad * 8);
            half8 af = pack8(*(const float4*)rp, *(const float4*)(rp + 4));
            #pragma unroll
            for (int t = 0; t < 8; t++) {
                half8 bf = *(const half8*)(&sW1[(((kb << 3) + t) * 64 + lane) * 8]);
                acc[t] = __builtin_amdgcn_mfma_f32_16x16x32_f16(af, bf, acc[t], 0, 0, 0);
            }
        }

        // epilogue 1: LN ; relu ; -> myM1
        #pragma unroll
        for (int r = 0; r < 4; r++) {
            float v[8], sum = 0.f, sq = 0.f;
            #pragma unroll
            for (int t = 0; t < 8; t++) {
                v[t] = acc[t][r] + b1c[t];
                sum += v[t]; sq += v[t] * v[t];
            }
            #pragma unroll
            for (int m = 1; m < 16; m <<= 1) {
                sum += __shfl_xor(sum, m, 64);
                sq  += __shfl_xor(sq, m, 64);
            }
            float mean = sum * (1.f / 128.f);
            float var = sq * (1.f / 128.f) - mean * mean;
            float rstd = rsqrtf(var + 1e-5f);
            half8 hv;
            #pragma unroll
            for (int t = 0; t < 8; t++) {
                float y = (v[t] - mean) * rstd * g1c[t] + be1c[t];
                hv[t] = (_Float16)fmaxf(y, 0.f);
            }
            *(half8*)(&myM1[(quad * 4 + r) * 136 + s * 8]) = hv;
        }

        // GEMM2
        f32x4 acc2[8];
        #pragma unroll
        for (int t = 0; t < 8; t++) { f32x4 z = {0.f, 0.f, 0.f, 0.f}; acc2[t] = z; }
        #pragma unroll
        for (int kb = 0; kb < 4; kb++) {
            half8 af = *(const half8*)(&myM1[s * 136 + kb * 32 + quad * 8]);
            #pragma unroll
            for (int t = 0; t < 8; t++) {
                half8 bf = *(const half8*)(&sW2[(((kb << 3) + t) * 64 + lane) * 8]);
                acc2[t] = __builtin_amdgcn_mfma_f32_16x16x32_f16(af, bf, acc2[t], 0, 0, 0);
            }
        }

        // epilogue 2: LN ; relu ; h += u
        #pragma unroll
        for (int r = 0; r < 4; r++) {
            int nn = nbase + quad * 4 + r;
            float v[8], sum = 0.f, sq = 0.f;
            #pragma unroll
            for (int t = 0; t < 8; t++) {
                v[t] = acc2[t][r] + b2c[t];
                sum += v[t]; sq += v[t] * v[t];
            }
            #pragma unroll
            for (int m = 1; m < 16; m <<= 1) {
                sum += __shfl_xor(sum, m, 64);
                sq  += __shfl_xor(sq, m, 64);
            }
            float mean = sum * (1.f / 128.f);
            float var = sq * (1.f / 128.f) - mean * mean;
            float rstd = rsqrtf(var + 1e-5f);
            if (nn < N_NODES) {
                float* hp = h + (size_t)nn * 128 + s * 8;
                float4 h0 = *(float4*)hp;
                float4 h1 = *(float4*)(hp + 4);
                float y[8];
                #pragma unroll
                for (int t = 0; t < 8; t++) {
                    float u = (v[t] - mean) * rstd * g2c[t] + be2c[t];
                    y[t] = fmaxf(u, 0.f);
                }
                h0.x += y[0]; h0.y += y[1]; h0.z += y[2]; h0.w += y[3];
                h1.x += y[4]; h1.y += y[5]; h1.z += y[6]; h1.w += y[7];
                *(float4*)hp = h0;
                *(float4*)(hp + 4) = h1;
            }
        }
    }
}

// ---------------- pool (parallel, segmented + atomics) ----------------
__global__ void pool_kernel(const float* __restrict__ h, const int* __restrict__ batch,
                            float* __restrict__ g) {
    const int CHUNK = 125;
    int blo = blockIdx.x * CHUNK;
    int bhi = blo + CHUNK; if (bhi > N_NODES) bhi = N_NODES;
    int j = threadIdx.x & 127;
    int half = threadIdx.x >> 7;
    float acc = 0.f; int cur = -1;
    for (int n = blo + half; n < bhi; n += 2) {
        int b = batch[n];
        if (b != cur) {
            if (cur >= 0) atomicAdd(&g[cur * 128 + j], acc);
            cur = b; acc = 0.f;
        }
        acc += h[(size_t)n * 128 + j];
    }
    if (cur >= 0) atomicAdd(&g[cur * 128 + j], acc);
}

// ---------------- pred ----------------
__global__ void pred_kernel(const float* __restrict__ g, const float* __restrict__ W1,
                            const float* __restrict__ b1, const float* __restrict__ W2,
                            const float* __restrict__ b2, float* __restrict__ out) {
    int b = blockIdx.x, j = threadIdx.x;
    float t = b1[j];
    for (int k = 0; k < 128; k++) t += g[b * 128 + k] * W1[k * 128 + j];
    t = fmaxf(t, 0.f);
    __shared__ float red[128];
    red[j] = t * W2[j];
    __syncthreads();
    for (int off = 64; off > 0; off >>= 1) {
        if (j < off) red[j] += red[j + off];
        __syncthreads();
    }
    if (j == 0) out[b] = red[0] + b2[0];
}

extern "C" void kernel_launch(void* const* d_in, const int* in_sizes, int n_in,
                              void* d_out, int out_size, void* d_ws, size_t ws_size,
                              hipStream_t stream) {
    const float* x      = (const float*)d_in[0];
    const float* pos    = (const float*)d_in[1];
    const int*   ei     = (const int*)d_in[2];
    const int*   batch  = (const int*)d_in[3];
    const float* emb_W  = (const float*)d_in[4];
    const float* emb_b  = (const float*)d_in[5];
    const float* msg_W1 = (const float*)d_in[6];
    const float* msg_b1 = (const float*)d_in[7];
    const float* msg_W2 = (const float*)d_in[8];
    const float* msg_b2 = (const float*)d_in[9];
    const float* upd_W1 = (const float*)d_in[10];
    const float* upd_b1 = (const float*)d_in[11];
    const float* upd_W2 = (const float*)d_in[12];
    const float* upd_b2 = (const float*)d_in[13];
    const float* msg_g1 = (const float*)d_in[14];
    const float* msg_be1= (const float*)d_in[15];
    const float* msg_g2 = (const float*)d_in[16];
    const float* msg_be2= (const float*)d_in[17];
    const float* upd_g1 = (const float*)d_in[18];
    const float* upd_be1= (const float*)d_in[19];
    const float* upd_g2 = (const float*)d_in[20];
    const float* upd_be2= (const float*)d_in[21];
    const float* pred_W1= (const float*)d_in[22];
    const float* pred_b1= (const float*)d_in[23];
    const float* pred_W2= (const float*)d_in[24];
    const float* pred_b2= (const float*)d_in[25];
    float* out = (float*)d_out;

    float* ws = (float*)d_ws;
    float*     h      = ws;                           // 3.2M floats
    _Float16*  U      = (_Float16*)(ws + 3200000);    // 3.2M halves
    _Float16*  S      = (_Float16*)(ws + 4800000);    // 3.2M halves
    float*     agg    = ws + 6400000;                 // 3.2M floats
    int*       rowptr = (int*)(ws + 19200000);        // 25,008
    int*       cursor = rowptr + 25008;               // 25,008 (doubles as cnt)
    int*       src_s  = cursor + 25008;               // 200,000
    int*       dst_s  = src_s + 200000;               // 200,000
    float*     dist_s = (float*)(dst_s + 200000);     // 200,000
    float*     g      = dist_s + 200000;              // 8,192

    hipMemsetAsync(cursor, 0, 25001 * sizeof(int), stream);
    hist_kernel<<<(N_EDGES + 255) / 256, 256, 0, stream>>>(ei, cursor);
    scan_kernel<<<1, 1024, 0, stream>>>(cursor, rowptr, cursor);
    scatter_kernel<<<(N_EDGES + 255) / 256, 256, 0, stream>>>(ei, pos, cursor, src_s, dst_s, dist_s);

    embed_kernel<<<4096, 256, 0, stream>>>(x, emb_W, emb_b, h);

    for (int l = 0; l < DEPTH; l++) {
        const float* W1l = msg_W1 + (size_t)l * 257 * 128;
        us_kernel<<<256, 512, 0, stream>>>(h, W1l, msg_b1 + l * 128, U, S);
        hipMemsetAsync(agg, 0, (size_t)N_NODES * 128 * sizeof(float), stream);
        edge_kernel<<<512, 256, 0, stream>>>(
            U, S, dist_s, src_s, dst_s,
            W1l + 256 * 128, msg_g1 + l * 128, msg_be1 + l * 128,
            msg_W2 + (size_t)l * 128 * 128, msg_b2 + l * 128, msg_g2 + l * 128, msg_be2 + l * 128,
            agg);
        upd_kernel<<<256, 512, 0, stream>>>(
            h, agg,
            upd_W1 + (size_t)l * 256 * 128, upd_b1 + l * 128, upd_g1 + l * 128, upd_be1 + l * 128,
            upd_W2 + (size_t)l * 128 * 128, upd_b2 + l * 128, upd_g2 + l * 128, upd_be2 + l * 128);
    }

    hipMemsetAsync(g, 0, N_GRAPHS * 128 * sizeof(float), stream);
    pool_kernel<<<200, 256, 0, stream>>>(h, batch, g);
    pred_kernel<<<64, 128, 0, stream>>>(g, pred_W1, pred_b1, pred_W2, pred_b2, out);
}

// Round 9
// 950.197 us; speedup vs baseline: 1.5961x; 1.1590x over previous
//
#include <hip/hip_runtime.h>
#include <hip/hip_bf16.h>

#define N_NODES 25000
#define N_EDGES 200000
#define N_GRAPHS 64
#define HID 128
#define DEPTH 5

typedef _Float16 half8 __attribute__((ext_vector_type(8)));
typedef _Float16 half2v __attribute__((ext_vector_type(2)));
typedef float f32x4 __attribute__((ext_vector_type(4)));

__device__ inline half8 pack8(float4 a, float4 b) {
    half8 r;
    r[0] = (_Float16)a.x; r[1] = (_Float16)a.y; r[2] = (_Float16)a.z; r[3] = (_Float16)a.w;
    r[4] = (_Float16)b.x; r[5] = (_Float16)b.y; r[6] = (_Float16)b.z; r[7] = (_Float16)b.w;
    return r;
}

// ---------------- embed ----------------
__global__ void embed_kernel(const float* __restrict__ x, const float* __restrict__ W,
                             const float* __restrict__ b, float* __restrict__ h) {
    for (int i = blockIdx.x * blockDim.x + threadIdx.x; i < N_NODES * HID;
         i += gridDim.x * blockDim.x) {
        int n = i >> 7, j = i & 127;
        float acc = b[j];
        #pragma unroll
        for (int k = 0; k < 16; k++) acc += x[n * 16 + k] * W[k * 128 + j];
        h[i] = acc;
    }
}

// ---------------- CSR build ----------------
__global__ void hist_kernel(const int* __restrict__ ei, int* __restrict__ cnt) {
    int e = blockIdx.x * blockDim.x + threadIdx.x;
    if (e < N_EDGES) atomicAdd(&cnt[ei[N_EDGES + e]], 1);
}

__global__ __launch_bounds__(1024)
void scan_kernel(const int* cnt, int* rowptr, int* cursor) {   // cnt may alias cursor
    __shared__ int swsum[16];
    __shared__ int stot;
    const int tid = threadIdx.x, wave = tid >> 6, lane = tid & 63;
    int carry = 0;
    for (int base = 0; base < N_NODES; base += 1024) {
        int i = base + tid;
        int v0 = (i < N_NODES) ? cnt[i] : 0;
        int v = v0;
        #pragma unroll
        for (int d = 1; d < 64; d <<= 1) {
            int t = __shfl_up(v, d, 64);
            if (lane >= d) v += t;
        }
        if (lane == 63) swsum[wave] = v;
        __syncthreads();
        if (wave == 0) {
            int sv = (lane < 16) ? swsum[lane] : 0;
            int si = sv;
            #pragma unroll
            for (int d = 1; d < 16; d <<= 1) {
                int t = __shfl_up(si, d, 64);
                if (lane >= d) si += t;
            }
            if (lane < 16) swsum[lane] = si - sv;
            if (lane == 15) stot = si;
        }
        __syncthreads();
        int excl = v - v0 + swsum[wave] + carry;
        if (i < N_NODES) { rowptr[i] = excl; cursor[i] = excl; }
        carry += stot;
        __syncthreads();
    }
    if (tid == 0) rowptr[N_NODES] = carry;
}

__global__ void scatter_kernel(const int* __restrict__ ei, const float* __restrict__ pos,
                               int* __restrict__ cursor, int* __restrict__ src_s,
                               int* __restrict__ dst_s, float* __restrict__ dist_s) {
    int e = blockIdx.x * blockDim.x + threadIdx.x;
    if (e < N_EDGES) {
        int s = ei[e], d = ei[N_EDGES + e];
        int p = atomicAdd(&cursor[d], 1);
        src_s[p] = s; dst_s[p] = d;
        float dx = pos[d * 3 + 0] - pos[s * 3 + 0];
        float dy = pos[d * 3 + 1] - pos[s * 3 + 1];
        float dz = pos[d * 3 + 2] - pos[s * 3 + 2];
        dist_s[p] = sqrtf(dx * dx + dy * dy + dz * dz);
    }
}

// ---------------- US precompute ----------------
__global__ __launch_bounds__(512, 2)
void us_kernel(const float* __restrict__ h, const float* __restrict__ W1,
               const float* __restrict__ bias1,
               _Float16* __restrict__ U, _Float16* __restrict__ S) {
    __shared__ _Float16 sW[32768];   // [kb(4)][tt(16)][lane(64)][j(8)]
    __shared__ float sB1[128];
    const int tid = threadIdx.x;
    for (int idx = tid; idx < 128 * 256; idx += 512) {
        int kk = idx >> 8, c = idx & 255;
        int cc = c & 127, s_ = cc >> 3, tt = (cc & 7) + ((c >> 7) << 3);
        float val = (c < 128) ? W1[kk * 128 + c] : W1[(128 + kk) * 128 + (c - 128)];
        int kb = kk >> 5, kq = (kk >> 3) & 3, j = kk & 7;
        sW[((((kb << 4) + tt) << 6) + ((kq << 4) | s_)) * 8 + j] = (_Float16)val;
    }
    if (tid < 128) sB1[tid] = bias1[tid];
    __syncthreads();

    const int w = tid >> 6, lane = tid & 63, quad = lane >> 4, s = lane & 15;
    float b1c[8];
    #pragma unroll
    for (int t = 0; t < 8; t++) b1c[t] = sB1[s * 8 + t];

    const int gw = blockIdx.x * 8 + w, nwaves = gridDim.x * 8;
    const int nwt = (N_NODES + 15) >> 4;
    for (int wt = gw; wt < nwt; wt += nwaves) {
        const int nbase = wt << 4;
        int n = nbase + s; if (n >= N_NODES) n = N_NODES - 1;
        f32x4 acc[16];
        #pragma unroll
        for (int tt = 0; tt < 16; tt++) { f32x4 z = {0.f, 0.f, 0.f, 0.f}; acc[tt] = z; }
        #pragma unroll
        for (int kb = 0; kb < 4; kb++) {
            const float* rp = h + (size_t)n * 128 + kb * 32 + quad * 8;
            half8 af = pack8(*(const float4*)rp, *(const float4*)(rp + 4));
            #pragma unroll
            for (int tt = 0; tt < 16; tt++) {
                half8 bf = *(const half8*)(&sW[((((kb << 4) + tt) << 6) + lane) * 8]);
                acc[tt] = __builtin_amdgcn_mfma_f32_16x16x32_f16(af, bf, acc[tt], 0, 0, 0);
            }
        }
        #pragma unroll
        for (int r = 0; r < 4; r++) {
            int nn = nbase + quad * 4 + r;
            if (nn < N_NODES) {
                half8 uv, sv;
                #pragma unroll
                for (int t = 0; t < 8; t++) {
                    uv[t] = (_Float16)(acc[t][r] + b1c[t]);
                    sv[t] = (_Float16)(acc[t + 8][r]);
                }
                *(half8*)(&U[(size_t)nn * 128 + s * 8]) = uv;
                *(half8*)(&S[(size_t)nn * 128 + s * 8]) = sv;
            }
        }
    }
}

// ---------------- edge kernel: MLP + run-segmented atomic scatter (LDS-staged indices) ----------------
// N_EDGES % 32 == 0 -> all 32-edge tiles are exact (no tail guards).
__global__ __launch_bounds__(256, 2)
void edge_kernel(const _Float16* __restrict__ U, const _Float16* __restrict__ S,
                 const float* __restrict__ dist_s, const int* __restrict__ src_s,
                 const int* __restrict__ dst_s,
                 const float* __restrict__ w256, const float* __restrict__ gam1,
                 const float* __restrict__ bet1,
                 const float* __restrict__ W2, const float* __restrict__ bias2,
                 const float* __restrict__ gam2, const float* __restrict__ bet2,
                 float* __restrict__ agg) {
    __shared__ _Float16 sW2[16384];    // [kb(4)][t(8)][lane(64)][j(8)]
    __shared__ _Float16 sM1[17408];    // 4 waves x [32 rows][136]
    __shared__ int   sDstA[4][34];     // 33 dsts (incl. next-tile first) per wave
    __shared__ int   sSrcA[4][32];
    __shared__ float sDistA[4][32];
    __shared__ float sB[768];

    const int tid = threadIdx.x;
    for (int idx = tid; idx < 128 * 128; idx += 256) {
        int k = idx >> 7, c = idx & 127;
        int s_ = c >> 3, t = c & 7, kb = k >> 5, kq = (k >> 3) & 3, j = k & 7;
        sW2[((((kb << 3) + t) << 6) + ((kq << 4) | s_)) * 8 + j] = (_Float16)W2[idx];
    }
    if (tid < 128) {
        sB[tid] = w256[tid];
        sB[128 + tid] = gam1[tid]; sB[256 + tid] = bet1[tid];
        sB[384 + tid] = bias2[tid]; sB[512 + tid] = gam2[tid]; sB[640 + tid] = bet2[tid];
    }
    __syncthreads();

    const int w = tid >> 6, lane = tid & 63, quad = lane >> 4, s = lane & 15;
    _Float16* myM1 = &sM1[w * (32 * 136)];
    int*   sDst  = sDstA[w];
    int*   sSrc  = sSrcA[w];
    float* sDist = sDistA[w];

    float w256c[8], g1c[8], be1c[8], b2c[8], g2c[8], be2c[8];
    #pragma unroll
    for (int t = 0; t < 8; t++) {
        int c = s * 8 + t;
        w256c[t] = sB[c]; g1c[t] = sB[128 + c]; be1c[t] = sB[256 + c];
        b2c[t] = sB[384 + c]; g2c[t] = sB[512 + c]; be2c[t] = sB[640 + c];
    }

    const int gw = blockIdx.x * 4 + w, nwaves = gridDim.x * 4;
    const int ewt = N_EDGES >> 5;   // exact
    for (int wt = gw; wt < ewt; wt += nwaves) {
        const int ebase = wt << 5;

        // phase 0: stage indices/dists into per-wave LDS (one coalesced pass)
        if (lane <= 32) {
            int e = ebase + lane;
            sDst[lane] = (e < N_EDGES) ? dst_s[e] : -1;
        } else {
            sSrc[lane - 33] = src_s[ebase + lane - 33];   // rows 0..30
        }
        if (lane < 32) sDist[lane] = dist_s[ebase + lane];
        else if (lane == 32) sSrc[31] = src_s[ebase + 31];
        // wave-uniform run-boundary mask (bit r: row r is last of its dst-run IN THIS TILE)
        bool bnd = (lane < 32) && (sDst[lane] != sDst[lane + 1]);
        unsigned mask = (unsigned)(__ballot(bnd) & 0xffffffffull);
        mask |= 0x80000000u;   // BUGFIX r8: always flush at tile end (runs spanning tiles)

        // phase A: gather U/S rows (16 outstanding 16B loads)
        float distA[8];
        half8 u8A[8], s8A[8];
        #pragma unroll
        for (int i = 0; i < 8; i++) {
            int row = (i >> 2) * 16 + quad * 4 + (i & 3);
            int d = sDst[row], si = sSrc[row];
            distA[i] = sDist[row];
            u8A[i] = *(const half8*)(&U[(size_t)d * 128 + s * 8]);
            s8A[i] = *(const half8*)(&S[(size_t)si * 128 + s * 8]);
        }

        // phase B: LN + relu -> myM1 (per-wave; in-order DS pipe, no barrier)
        #pragma unroll
        for (int i = 0; i < 8; i++) {
            float v[8], sum = 0.f, sq = 0.f;
            #pragma unroll
            for (int t = 0; t < 8; t++) {
                v[t] = (float)u8A[i][t] + (float)s8A[i][t] + distA[i] * w256c[t];
                sum += v[t]; sq += v[t] * v[t];
            }
            #pragma unroll
            for (int m = 1; m < 16; m <<= 1) {
                sum += __shfl_xor(sum, m, 64);
                sq  += __shfl_xor(sq, m, 64);
            }
            float mean = sum * (1.f / 128.f);
            float var = sq * (1.f / 128.f) - mean * mean;
            float rstd = rsqrtf(var + 1e-5f);
            half8 hv;
            #pragma unroll
            for (int t = 0; t < 8; t++) {
                float y = (v[t] - mean) * rstd * g1c[t] + be1c[t];
                hv[t] = (_Float16)fmaxf(y, 0.f);
            }
            *(half8*)(&myM1[((i >> 2) * 16 + quad * 4 + (i & 3)) * 136 + s * 8]) = hv;
        }

        // GEMM2
        f32x4 acc2[2][8];
        #pragma unroll
        for (int mt = 0; mt < 2; mt++)
            #pragma unroll
            for (int t = 0; t < 8; t++) { f32x4 z = {0.f, 0.f, 0.f, 0.f}; acc2[mt][t] = z; }
        #pragma unroll
        for (int kb = 0; kb < 4; kb++) {
            half8 af[2];
            #pragma unroll
            for (int mt = 0; mt < 2; mt++)
                af[mt] = *(const half8*)(&myM1[(mt * 16 + s) * 136 + kb * 32 + quad * 8]);
            #pragma unroll
            for (int t = 0; t < 8; t++) {
                half8 bf = *(const half8*)(&sW2[(((kb << 3) + t) * 64 + lane) * 8]);
                acc2[0][t] = __builtin_amdgcn_mfma_f32_16x16x32_f16(af[0], bf, acc2[0][t], 0, 0, 0);
                acc2[1][t] = __builtin_amdgcn_mfma_f32_16x16x32_f16(af[1], bf, acc2[1][t], 0, 0, 0);
            }
        }

        // epilogue 2: LN ; relu ; m2 rows -> myM1 (overwrite m1; GEMM2 reads done)
        #pragma unroll
        for (int mt = 0; mt < 2; mt++) {
            #pragma unroll
            for (int r = 0; r < 4; r++) {
                float v[8], sum = 0.f, sq = 0.f;
                #pragma unroll
                for (int t = 0; t < 8; t++) {
                    v[t] = acc2[mt][t][r] + b2c[t];
                    sum += v[t]; sq += v[t] * v[t];
                }
                #pragma unroll
                for (int m = 1; m < 16; m <<= 1) {
                    sum += __shfl_xor(sum, m, 64);
                    sq  += __shfl_xor(sq, m, 64);
                }
                float mean = sum * (1.f / 128.f);
                float var = sq * (1.f / 128.f) - mean * mean;
                float rstd = rsqrtf(var + 1e-5f);
                half8 hv;
                #pragma unroll
                for (int t = 0; t < 8; t++) {
                    float y = (v[t] - mean) * rstd * g2c[t] + be2c[t];
                    hv[t] = (_Float16)fmaxf(y, 0.f);
                }
                *(half8*)(&myM1[(mt * 16 + quad * 4 + r) * 136 + s * 8]) = hv;
            }
        }

        // phase C: run-segmented reduction; lane owns cols {2*lane, 2*lane+1}
        // per row: 1 ds_read_b32 + 1 v_pk_add_f16; flush under wave-uniform scalar branch
        {
            const int col2 = lane * 2;
            half2v acc; acc[0] = (_Float16)0.f; acc[1] = (_Float16)0.f;
            for (int row = 0; row < 32; row++) {
                half2v v = *(const half2v*)(&myM1[row * 136 + col2]);
                acc += v;
                if ((mask >> row) & 1u) {                 // wave-uniform
                    int d = sDst[row];                    // LDS broadcast
                    float a0 = (float)acc[0], a1 = (float)acc[1];
                    if (a0 != 0.f) atomicAdd(&agg[(size_t)d * 128 + col2], a0);
                    if (a1 != 0.f) atomicAdd(&agg[(size_t)d * 128 + col2 + 1], a1);
                    acc[0] = (_Float16)0.f; acc[1] = (_Float16)0.f;
                }
            }
        }
    }
}

// ---------------- upd: node-MLP + residual (agg from global f32) ----------------
__global__ __launch_bounds__(512, 2)
void upd_kernel(float* __restrict__ h, const float* __restrict__ agg,
                const float* __restrict__ W1, const float* __restrict__ bias1,
                const float* __restrict__ gam1, const float* __restrict__ bet1,
                const float* __restrict__ W2, const float* __restrict__ bias2,
                const float* __restrict__ gam2, const float* __restrict__ bet2) {
    __shared__ _Float16 sW1[32768];
    __shared__ _Float16 sW2[16384];
    __shared__ _Float16 sM1[17408];   // 8 waves x [16 rows][136]
    __shared__ float sB[768];

    const int tid = threadIdx.x;
    for (int idx = tid; idx < 256 * 128; idx += 512) {
        int k = idx >> 7, c = idx & 127;
        int s_ = c >> 3, t = c & 7, kb = k >> 5, kq = (k >> 3) & 3, j = k & 7;
        sW1[((((kb << 3) + t) << 6) + ((kq << 4) | s_)) * 8 + j] = (_Float16)W1[idx];
    }
    for (int idx = tid; idx < 128 * 128; idx += 512) {
        int k = idx >> 7, c = idx & 127;
        int s_ = c >> 3, t = c & 7, kb = k >> 5, kq = (k >> 3) & 3, j = k & 7;
        sW2[((((kb << 3) + t) << 6) + ((kq << 4) | s_)) * 8 + j] = (_Float16)W2[idx];
    }
    if (tid < 128) {
        sB[tid] = bias1[tid]; sB[128 + tid] = gam1[tid]; sB[256 + tid] = bet1[tid];
        sB[384 + tid] = bias2[tid]; sB[512 + tid] = gam2[tid]; sB[640 + tid] = bet2[tid];
    }
    __syncthreads();

    const int w = tid >> 6, lane = tid & 63, quad = lane >> 4, s = lane & 15;
    _Float16* myM1 = &sM1[w * (16 * 136)];

    float b1c[8], g1c[8], be1c[8], b2c[8], g2c[8], be2c[8];
    #pragma unroll
    for (int t = 0; t < 8; t++) {
        int c = s * 8 + t;
        b1c[t] = sB[c]; g1c[t] = sB[128 + c]; be1c[t] = sB[256 + c];
        b2c[t] = sB[384 + c]; g2c[t] = sB[512 + c]; be2c[t] = sB[640 + c];
    }

    const int gw = blockIdx.x * 8 + w, nwaves = gridDim.x * 8;
    const int nwt = (N_NODES + 15) >> 4;
    for (int wt = gw; wt < nwt; wt += nwaves) {
        const int nbase = wt << 4;
        int n = nbase + s; if (n >= N_NODES) n = N_NODES - 1;

        // GEMM1: A = [h[n] | agg[n]] straight from global f32
        f32x4 acc[8];
        #pragma unroll
        for (int t = 0; t < 8; t++) { f32x4 z = {0.f, 0.f, 0.f, 0.f}; acc[t] = z; }
        #pragma unroll
        for (int kb = 0; kb < 8; kb++) {
            const float* rp = (kb < 4) ? (h + (size_t)n * 128 + kb * 32 + quad * 8)
                                       : (agg + (size_t)n * 128 + (kb - 4) * 32 + quad * 8);
            half8 af = pack8(*(const float4*)rp, *(const float4*)(rp + 4));
            #pragma unroll
            for (int t = 0; t < 8; t++) {
                half8 bf = *(const half8*)(&sW1[(((kb << 3) + t) * 64 + lane) * 8]);
                acc[t] = __builtin_amdgcn_mfma_f32_16x16x32_f16(af, bf, acc[t], 0, 0, 0);
            }
        }

        // epilogue 1: LN ; relu ; -> myM1
        #pragma unroll
        for (int r = 0; r < 4; r++) {
            float v[8], sum = 0.f, sq = 0.f;
            #pragma unroll
            for (int t = 0; t < 8; t++) {
                v[t] = acc[t][r] + b1c[t];
                sum += v[t]; sq += v[t] * v[t];
            }
            #pragma unroll
            for (int m = 1; m < 16; m <<= 1) {
                sum += __shfl_xor(sum, m, 64);
                sq  += __shfl_xor(sq, m, 64);
            }
            float mean = sum * (1.f / 128.f);
            float var = sq * (1.f / 128.f) - mean * mean;
            float rstd = rsqrtf(var + 1e-5f);
            half8 hv;
            #pragma unroll
            for (int t = 0; t < 8; t++) {
                float y = (v[t] - mean) * rstd * g1c[t] + be1c[t];
                hv[t] = (_Float16)fmaxf(y, 0.f);
            }
            *(half8*)(&myM1[(quad * 4 + r) * 136 + s * 8]) = hv;
        }

        // GEMM2
        f32x4 acc2[8];
        #pragma unroll
        for (int t = 0; t < 8; t++) { f32x4 z = {0.f, 0.f, 0.f, 0.f}; acc2[t] = z; }
        #pragma unroll
        for (int kb = 0; kb < 4; kb++) {
            half8 af = *(const half8*)(&myM1[s * 136 + kb * 32 + quad * 8]);
            #pragma unroll
            for (int t = 0; t < 8; t++) {
                half8 bf = *(const half8*)(&sW2[(((kb << 3) + t) * 64 + lane) * 8]);
                acc2[t] = __builtin_amdgcn_mfma_f32_16x16x32_f16(af, bf, acc2[t], 0, 0, 0);
            }
        }

        // epilogue 2: LN ; relu ; h += u
        #pragma unroll
        for (int r = 0; r < 4; r++) {
            int nn = nbase + quad * 4 + r;
            float v[8], sum = 0.f, sq = 0.f;
            #pragma unroll
            for (int t = 0; t < 8; t++) {
                v[t] = acc2[t][r] + b2c[t];
                sum += v[t]; sq += v[t] * v[t];
            }
            #pragma unroll
            for (int m = 1; m < 16; m <<= 1) {
                sum += __shfl_xor(sum, m, 64);
                sq  += __shfl_xor(sq, m, 64);
            }
            float mean = sum * (1.f / 128.f);
            float var = sq * (1.f / 128.f) - mean * mean;
            float rstd = rsqrtf(var + 1e-5f);
            if (nn < N_NODES) {
                float* hp = h + (size_t)nn * 128 + s * 8;
                float4 h0 = *(float4*)hp;
                float4 h1 = *(float4*)(hp + 4);
                float y[8];
                #pragma unroll
                for (int t = 0; t < 8; t++) {
                    float u = (v[t] - mean) * rstd * g2c[t] + be2c[t];
                    y[t] = fmaxf(u, 0.f);
                }
                h0.x += y[0]; h0.y += y[1]; h0.z += y[2]; h0.w += y[3];
                h1.x += y[4]; h1.y += y[5]; h1.z += y[6]; h1.w += y[7];
                *(float4*)hp = h0;
                *(float4*)(hp + 4) = h1;
            }
        }
    }
}

// ---------------- pool (parallel, segmented + atomics) ----------------
__global__ void pool_kernel(const float* __restrict__ h, const int* __restrict__ batch,
                            float* __restrict__ g) {
    const int CHUNK = 125;
    int blo = blockIdx.x * CHUNK;
    int bhi = blo + CHUNK; if (bhi > N_NODES) bhi = N_NODES;
    int j = threadIdx.x & 127;
    int half = threadIdx.x >> 7;
    float acc = 0.f; int cur = -1;
    for (int n = blo + half; n < bhi; n += 2) {
        int b = batch[n];
        if (b != cur) {
            if (cur >= 0) atomicAdd(&g[cur * 128 + j], acc);
            cur = b; acc = 0.f;
        }
        acc += h[(size_t)n * 128 + j];
    }
    if (cur >= 0) atomicAdd(&g[cur * 128 + j], acc);
}

// ---------------- pred ----------------
__global__ void pred_kernel(const float* __restrict__ g, const float* __restrict__ W1,
                            const float* __restrict__ b1, const float* __restrict__ W2,
                            const float* __restrict__ b2, float* __restrict__ out) {
    int b = blockIdx.x, j = threadIdx.x;
    float t = b1[j];
    for (int k = 0; k < 128; k++) t += g[b * 128 + k] * W1[k * 128 + j];
    t = fmaxf(t, 0.f);
    __shared__ float red[128];
    red[j] = t * W2[j];
    __syncthreads();
    for (int off = 64; off > 0; off >>= 1) {
        if (j < off) red[j] += red[j + off];
        __syncthreads();
    }
    if (j == 0) out[b] = red[0] + b2[0];
}

extern "C" void kernel_launch(void* const* d_in, const int* in_sizes, int n_in,
                              void* d_out, int out_size, void* d_ws, size_t ws_size,
                              hipStream_t stream) {
    const float* x      = (const float*)d_in[0];
    const float* pos    = (const float*)d_in[1];
    const int*   ei     = (const int*)d_in[2];
    const int*   batch  = (const int*)d_in[3];
    const float* emb_W  = (const float*)d_in[4];
    const float* emb_b  = (const float*)d_in[5];
    const float* msg_W1 = (const float*)d_in[6];
    const float* msg_b1 = (const float*)d_in[7];
    const float* msg_W2 = (const float*)d_in[8];
    const float* msg_b2 = (const float*)d_in[9];
    const float* upd_W1 = (const float*)d_in[10];
    const float* upd_b1 = (const float*)d_in[11];
    const float* upd_W2 = (const float*)d_in[12];
    const float* upd_b2 = (const float*)d_in[13];
    const float* msg_g1 = (const float*)d_in[14];
    const float* msg_be1= (const float*)d_in[15];
    const float* msg_g2 = (const float*)d_in[16];
    const float* msg_be2= (const float*)d_in[17];
    const float* upd_g1 = (const float*)d_in[18];
    const float* upd_be1= (const float*)d_in[19];
    const float* upd_g2 = (const float*)d_in[20];
    const float* upd_be2= (const float*)d_in[21];
    const float* pred_W1= (const float*)d_in[22];
    const float* pred_b1= (const float*)d_in[23];
    const float* pred_W2= (const float*)d_in[24];
    const float* pred_b2= (const float*)d_in[25];
    float* out = (float*)d_out;

    float* ws = (float*)d_ws;
    float*     h      = ws;                           // 3.2M floats
    _Float16*  U      = (_Float16*)(ws + 3200000);    // 3.2M halves
    _Float16*  S      = (_Float16*)(ws + 4800000);    // 3.2M halves
    float*     agg    = ws + 6400000;                 // 3.2M floats
    int*       rowptr = (int*)(ws + 19200000);        // 25,008
    int*       cursor = rowptr + 25008;               // 25,008 (doubles as cnt)
    int*       src_s  = cursor + 25008;               // 200,000
    int*       dst_s  = src_s + 200000;               // 200,000
    float*     dist_s = (float*)(dst_s + 200000);     // 200,000
    float*     g      = dist_s + 200000;              // 8,192

    hipMemsetAsync(cursor, 0, 25001 * sizeof(int), stream);
    hist_kernel<<<(N_EDGES + 255) / 256, 256, 0, stream>>>(ei, cursor);
    scan_kernel<<<1, 1024, 0, stream>>>(cursor, rowptr, cursor);
    scatter_kernel<<<(N_EDGES + 255) / 256, 256, 0, stream>>>(ei, pos, cursor, src_s, dst_s, dist_s);

    embed_kernel<<<4096, 256, 0, stream>>>(x, emb_W, emb_b, h);

    for (int l = 0; l < DEPTH; l++) {
        const float* W1l = msg_W1 + (size_t)l * 257 * 128;
        us_kernel<<<256, 512, 0, stream>>>(h, W1l, msg_b1 + l * 128, U, S);
        hipMemsetAsync(agg, 0, (size_t)N_NODES * 128 * sizeof(float), stream);
        edge_kernel<<<512, 256, 0, stream>>>(
            U, S, dist_s, src_s, dst_s,
            W1l + 256 * 128, msg_g1 + l * 128, msg_be1 + l * 128,
            msg_W2 + (size_t)l * 128 * 128, msg_b2 + l * 128, msg_g2 + l * 128, msg_be2 + l * 128,
            agg);
        upd_kernel<<<256, 512, 0, stream>>>(
            h, agg,
            upd_W1 + (size_t)l * 256 * 128, upd_b1 + l * 128, upd_g1 + l * 128, upd_be1 + l * 128,
            upd_W2 + (size_t)l * 128 * 128, upd_b2 + l * 128, upd_g2 + l * 128, upd_be2 + l * 128);
    }

    hipMemsetAsync(g, 0, N_GRAPHS * 128 * sizeof(float), stream);
    pool_kernel<<<200, 256, 0, stream>>>(h, batch, g);
    pred_kernel<<<64, 128, 0, stream>>>(g, pred_W1, pred_b1, pred_W2, pred_b2, out);
}

// Round 10
// 943.189 us; speedup vs baseline: 1.6080x; 1.0074x over previous
//
#include <hip/hip_runtime.h>
#include <hip/hip_bf16.h>

#define N_NODES 25000
#define N_EDGES 200000
#define N_GRAPHS 64
#define HID 128
#define DEPTH 5

typedef _Float16 half8 __attribute__((ext_vector_type(8)));
typedef _Float16 half2v __attribute__((ext_vector_type(2)));
typedef float f32x4 __attribute__((ext_vector_type(4)));

__device__ inline half8 pack8(float4 a, float4 b) {
    half8 r;
    r[0] = (_Float16)a.x; r[1] = (_Float16)a.y; r[2] = (_Float16)a.z; r[3] = (_Float16)a.w;
    r[4] = (_Float16)b.x; r[5] = (_Float16)b.y; r[6] = (_Float16)b.z; r[7] = (_Float16)b.w;
    return r;
}

// ---------------- embed ----------------
__global__ void embed_kernel(const float* __restrict__ x, const float* __restrict__ W,
                             const float* __restrict__ b, float* __restrict__ h) {
    for (int i = blockIdx.x * blockDim.x + threadIdx.x; i < N_NODES * HID;
         i += gridDim.x * blockDim.x) {
        int n = i >> 7, j = i & 127;
        float acc = b[j];
        #pragma unroll
        for (int k = 0; k < 16; k++) acc += x[n * 16 + k] * W[k * 128 + j];
        h[i] = acc;
    }
}

// ---------------- CSR build ----------------
__global__ void hist_kernel(const int* __restrict__ ei, int* __restrict__ cnt) {
    int e = blockIdx.x * blockDim.x + threadIdx.x;
    if (e < N_EDGES) atomicAdd(&cnt[ei[N_EDGES + e]], 1);
}

__global__ __launch_bounds__(1024)
void scan_kernel(const int* cnt, int* rowptr, int* cursor) {   // cnt may alias cursor
    __shared__ int swsum[16];
    __shared__ int stot;
    const int tid = threadIdx.x, wave = tid >> 6, lane = tid & 63;
    int carry = 0;
    for (int base = 0; base < N_NODES; base += 1024) {
        int i = base + tid;
        int v0 = (i < N_NODES) ? cnt[i] : 0;
        int v = v0;
        #pragma unroll
        for (int d = 1; d < 64; d <<= 1) {
            int t = __shfl_up(v, d, 64);
            if (lane >= d) v += t;
        }
        if (lane == 63) swsum[wave] = v;
        __syncthreads();
        if (wave == 0) {
            int sv = (lane < 16) ? swsum[lane] : 0;
            int si = sv;
            #pragma unroll
            for (int d = 1; d < 16; d <<= 1) {
                int t = __shfl_up(si, d, 64);
                if (lane >= d) si += t;
            }
            if (lane < 16) swsum[lane] = si - sv;
            if (lane == 15) stot = si;
        }
        __syncthreads();
        int excl = v - v0 + swsum[wave] + carry;
        if (i < N_NODES) { rowptr[i] = excl; cursor[i] = excl; }
        carry += stot;
        __syncthreads();
    }
    if (tid == 0) rowptr[N_NODES] = carry;
}

__global__ void scatter_kernel(const int* __restrict__ ei, const float* __restrict__ pos,
                               int* __restrict__ cursor, int* __restrict__ src_s,
                               int* __restrict__ dst_s, float* __restrict__ dist_s) {
    int e = blockIdx.x * blockDim.x + threadIdx.x;
    if (e < N_EDGES) {
        int s = ei[e], d = ei[N_EDGES + e];
        int p = atomicAdd(&cursor[d], 1);
        src_s[p] = s; dst_s[p] = d;
        float dx = pos[d * 3 + 0] - pos[s * 3 + 0];
        float dy = pos[d * 3 + 1] - pos[s * 3 + 1];
        float dz = pos[d * 3 + 2] - pos[s * 3 + 2];
        dist_s[p] = sqrtf(dx * dx + dy * dy + dz * dz);
    }
}

// ---------------- US precompute (two-pass acc to stay under 128 VGPR @ 2 blk/CU) ----------------
__global__ __launch_bounds__(512, 2)
void us_kernel(const float* __restrict__ h, const float* __restrict__ W1,
               const float* __restrict__ bias1,
               _Float16* __restrict__ U, _Float16* __restrict__ S) {
    __shared__ _Float16 sW[32768];   // [kb(4)][tt(16)][lane(64)][j(8)]
    __shared__ float sB1[128];
    const int tid = threadIdx.x;
    for (int idx = tid; idx < 128 * 256; idx += 512) {
        int kk = idx >> 8, c = idx & 255;
        int cc = c & 127, s_ = cc >> 3, tt = (cc & 7) + ((c >> 7) << 3);
        float val = (c < 128) ? W1[kk * 128 + c] : W1[(128 + kk) * 128 + (c - 128)];
        int kb = kk >> 5, kq = (kk >> 3) & 3, j = kk & 7;
        sW[((((kb << 4) + tt) << 6) + ((kq << 4) | s_)) * 8 + j] = (_Float16)val;
    }
    if (tid < 128) sB1[tid] = bias1[tid];
    __syncthreads();

    const int w = tid >> 6, lane = tid & 63, quad = lane >> 4, s = lane & 15;
    float b1c[8];
    #pragma unroll
    for (int t = 0; t < 8; t++) b1c[t] = sB1[s * 8 + t];

    const int gw = blockIdx.x * 8 + w, nwaves = gridDim.x * 8;
    const int nwt = (N_NODES + 15) >> 4;
    for (int wt = gw; wt < nwt; wt += nwaves) {
        const int nbase = wt << 4;
        int n = nbase + s; if (n >= N_NODES) n = N_NODES - 1;

        // hoist A-fragments once (16 VGPRs)
        half8 af[4];
        #pragma unroll
        for (int kb = 0; kb < 4; kb++) {
            const float* rp = h + (size_t)n * 128 + kb * 32 + quad * 8;
            af[kb] = pack8(*(const float4*)rp, *(const float4*)(rp + 4));
        }

        // pass 0: U (cols via tt 0..7, +bias) ; pass 1: S (tt 8..15)
        #pragma unroll
        for (int uhalf = 0; uhalf < 2; uhalf++) {
            f32x4 acc[8];
            #pragma unroll
            for (int t = 0; t < 8; t++) { f32x4 z = {0.f, 0.f, 0.f, 0.f}; acc[t] = z; }
            #pragma unroll
            for (int kb = 0; kb < 4; kb++) {
                #pragma unroll
                for (int t = 0; t < 8; t++) {
                    half8 bf = *(const half8*)(&sW[((((kb << 4) + (uhalf * 8 + t)) << 6) + lane) * 8]);
                    acc[t] = __builtin_amdgcn_mfma_f32_16x16x32_f16(af[kb], bf, acc[t], 0, 0, 0);
                }
            }
            _Float16* dstbuf = uhalf ? S : U;
            #pragma unroll
            for (int r = 0; r < 4; r++) {
                int nn = nbase + quad * 4 + r;
                if (nn < N_NODES) {
                    half8 ov;
                    #pragma unroll
                    for (int t = 0; t < 8; t++)
                        ov[t] = (_Float16)(acc[t][r] + (uhalf ? 0.f : b1c[t]));
                    *(half8*)(&dstbuf[(size_t)nn * 128 + s * 8]) = ov;
                }
            }
        }
    }
}

// ---------------- edge kernel: MLP + run-segmented atomic scatter (LDS-staged indices) ----------------
// N_EDGES % 32 == 0 -> all 32-edge tiles are exact (no tail guards).
__global__ __launch_bounds__(256, 2)
void edge_kernel(const _Float16* __restrict__ U, const _Float16* __restrict__ S,
                 const float* __restrict__ dist_s, const int* __restrict__ src_s,
                 const int* __restrict__ dst_s,
                 const float* __restrict__ w256, const float* __restrict__ gam1,
                 const float* __restrict__ bet1,
                 const float* __restrict__ W2, const float* __restrict__ bias2,
                 const float* __restrict__ gam2, const float* __restrict__ bet2,
                 float* __restrict__ agg) {
    __shared__ _Float16 sW2[16384];    // [kb(4)][t(8)][lane(64)][j(8)]
    __shared__ _Float16 sM1[17408];    // 4 waves x [32 rows][136]
    __shared__ int   sDstA[4][34];
    __shared__ int   sSrcA[4][32];
    __shared__ float sDistA[4][32];
    __shared__ float sB[768];

    const int tid = threadIdx.x;
    for (int idx = tid; idx < 128 * 128; idx += 256) {
        int k = idx >> 7, c = idx & 127;
        int s_ = c >> 3, t = c & 7, kb = k >> 5, kq = (k >> 3) & 3, j = k & 7;
        sW2[((((kb << 3) + t) << 6) + ((kq << 4) | s_)) * 8 + j] = (_Float16)W2[idx];
    }
    if (tid < 128) {
        sB[tid] = w256[tid];
        sB[128 + tid] = gam1[tid]; sB[256 + tid] = bet1[tid];
        sB[384 + tid] = bias2[tid]; sB[512 + tid] = gam2[tid]; sB[640 + tid] = bet2[tid];
    }
    __syncthreads();

    const int w = tid >> 6, lane = tid & 63, quad = lane >> 4, s = lane & 15;
    _Float16* myM1 = &sM1[w * (32 * 136)];
    int*   sDst  = sDstA[w];
    int*   sSrc  = sSrcA[w];
    float* sDist = sDistA[w];

    float w256c[8], g1c[8], be1c[8], b2c[8], g2c[8], be2c[8];
    #pragma unroll
    for (int t = 0; t < 8; t++) {
        int c = s * 8 + t;
        w256c[t] = sB[c]; g1c[t] = sB[128 + c]; be1c[t] = sB[256 + c];
        b2c[t] = sB[384 + c]; g2c[t] = sB[512 + c]; be2c[t] = sB[640 + c];
    }

    const int gw = blockIdx.x * 4 + w, nwaves = gridDim.x * 4;
    const int ewt = N_EDGES >> 5;   // exact
    for (int wt = gw; wt < ewt; wt += nwaves) {
        const int ebase = wt << 5;

        // phase 0: stage indices/dists into per-wave LDS (one coalesced pass)
        if (lane <= 32) {
            int e = ebase + lane;
            sDst[lane] = (e < N_EDGES) ? dst_s[e] : -1;
        } else {
            sSrc[lane - 33] = src_s[ebase + lane - 33];   // rows 0..30
        }
        if (lane < 32) sDist[lane] = dist_s[ebase + lane];
        else if (lane == 32) sSrc[31] = src_s[ebase + 31];
        // wave-uniform run-boundary mask (bit r: row r is last of its dst-run IN THIS TILE)
        bool bnd = (lane < 32) && (sDst[lane] != sDst[lane + 1]);
        unsigned mask = (unsigned)(__ballot(bnd) & 0xffffffffull);
        mask |= 0x80000000u;   // always flush at tile end (runs spanning tiles)

        // phase A: gather U/S rows (16 outstanding 16B loads)
        float distA[8];
        half8 u8A[8], s8A[8];
        #pragma unroll
        for (int i = 0; i < 8; i++) {
            int row = (i >> 2) * 16 + quad * 4 + (i & 3);
            int d = sDst[row], si = sSrc[row];
            distA[i] = sDist[row];
            u8A[i] = *(const half8*)(&U[(size_t)d * 128 + s * 8]);
            s8A[i] = *(const half8*)(&S[(size_t)si * 128 + s * 8]);
        }

        // phase B: LN + relu -> myM1 (per-wave; in-order DS pipe, no barrier)
        #pragma unroll
        for (int i = 0; i < 8; i++) {
            float v[8], sum = 0.f, sq = 0.f;
            #pragma unroll
            for (int t = 0; t < 8; t++) {
                v[t] = (float)u8A[i][t] + (float)s8A[i][t] + distA[i] * w256c[t];
                sum += v[t]; sq += v[t] * v[t];
            }
            #pragma unroll
            for (int m = 1; m < 16; m <<= 1) {
                sum += __shfl_xor(sum, m, 64);
                sq  += __shfl_xor(sq, m, 64);
            }
            float mean = sum * (1.f / 128.f);
            float var = sq * (1.f / 128.f) - mean * mean;
            float rstd = rsqrtf(var + 1e-5f);
            half8 hv;
            #pragma unroll
            for (int t = 0; t < 8; t++) {
                float y = (v[t] - mean) * rstd * g1c[t] + be1c[t];
                hv[t] = (_Float16)fmaxf(y, 0.f);
            }
            *(half8*)(&myM1[((i >> 2) * 16 + quad * 4 + (i & 3)) * 136 + s * 8]) = hv;
        }

        // GEMM2
        f32x4 acc2[2][8];
        #pragma unroll
        for (int mt = 0; mt < 2; mt++)
            #pragma unroll
            for (int t = 0; t < 8; t++) { f32x4 z = {0.f, 0.f, 0.f, 0.f}; acc2[mt][t] = z; }
        #pragma unroll
        for (int kb = 0; kb < 4; kb++) {
            half8 af[2];
            #pragma unroll
            for (int mt = 0; mt < 2; mt++)
                af[mt] = *(const half8*)(&myM1[(mt * 16 + s) * 136 + kb * 32 + quad * 8]);
            #pragma unroll
            for (int t = 0; t < 8; t++) {
                half8 bf = *(const half8*)(&sW2[(((kb << 3) + t) * 64 + lane) * 8]);
                acc2[0][t] = __builtin_amdgcn_mfma_f32_16x16x32_f16(af[0], bf, acc2[0][t], 0, 0, 0);
                acc2[1][t] = __builtin_amdgcn_mfma_f32_16x16x32_f16(af[1], bf, acc2[1][t], 0, 0, 0);
            }
        }

        // epilogue 2: LN ; relu ; m2 rows -> myM1 (overwrite m1; GEMM2 reads done)
        #pragma unroll
        for (int mt = 0; mt < 2; mt++) {
            #pragma unroll
            for (int r = 0; r < 4; r++) {
                float v[8], sum = 0.f, sq = 0.f;
                #pragma unroll
                for (int t = 0; t < 8; t++) {
                    v[t] = acc2[mt][t][r] + b2c[t];
                    sum += v[t]; sq += v[t] * v[t];
                }
                #pragma unroll
                for (int m = 1; m < 16; m <<= 1) {
                    sum += __shfl_xor(sum, m, 64);
                    sq  += __shfl_xor(sq, m, 64);
                }
                float mean = sum * (1.f / 128.f);
                float var = sq * (1.f / 128.f) - mean * mean;
                float rstd = rsqrtf(var + 1e-5f);
                half8 hv;
                #pragma unroll
                for (int t = 0; t < 8; t++) {
                    float y = (v[t] - mean) * rstd * g2c[t] + be2c[t];
                    hv[t] = (_Float16)fmaxf(y, 0.f);
                }
                *(half8*)(&myM1[(mt * 16 + quad * 4 + r) * 136 + s * 8]) = hv;
            }
        }

        // phase C: run-segmented reduction; lane owns cols {2*lane, 2*lane+1}
        {
            const int col2 = lane * 2;
            half2v acc; acc[0] = (_Float16)0.f; acc[1] = (_Float16)0.f;
            for (int row = 0; row < 32; row++) {
                half2v v = *(const half2v*)(&myM1[row * 136 + col2]);
                acc += v;
                if ((mask >> row) & 1u) {                 // wave-uniform
                    int d = sDst[row];                    // LDS broadcast
                    float a0 = (float)acc[0], a1 = (float)acc[1];
                    if (a0 != 0.f) atomicAdd(&agg[(size_t)d * 128 + col2], a0);
                    if (a1 != 0.f) atomicAdd(&agg[(size_t)d * 128 + col2 + 1], a1);
                    acc[0] = (_Float16)0.f; acc[1] = (_Float16)0.f;
                }
            }
        }
    }
}

// ---------------- upd: node-MLP + residual (agg from global f32) ----------------
// LDS (133 KB) caps at 1 block/CU = 2 waves/SIMD anyway -> declare min-waves=1 so the
// VGPR budget is 256/wave and the compiler does NOT spill (the (512,2) cap of 128 spilled
// ~112 MB of scratch traffic per dispatch - r9 counters).
__global__ __launch_bounds__(512, 1)
void upd_kernel(float* __restrict__ h, const float* __restrict__ agg,
                const float* __restrict__ W1, const float* __restrict__ bias1,
                const float* __restrict__ gam1, const float* __restrict__ bet1,
                const float* __restrict__ W2, const float* __restrict__ bias2,
                const float* __restrict__ gam2, const float* __restrict__ bet2) {
    __shared__ _Float16 sW1[32768];
    __shared__ _Float16 sW2[16384];
    __shared__ _Float16 sM1[17408];   // 8 waves x [16 rows][136]
    __shared__ float sB[768];

    const int tid = threadIdx.x;
    for (int idx = tid; idx < 256 * 128; idx += 512) {
        int k = idx >> 7, c = idx & 127;
        int s_ = c >> 3, t = c & 7, kb = k >> 5, kq = (k >> 3) & 3, j = k & 7;
        sW1[((((kb << 3) + t) << 6) + ((kq << 4) | s_)) * 8 + j] = (_Float16)W1[idx];
    }
    for (int idx = tid; idx < 128 * 128; idx += 512) {
        int k = idx >> 7, c = idx & 127;
        int s_ = c >> 3, t = c & 7, kb = k >> 5, kq = (k >> 3) & 3, j = k & 7;
        sW2[((((kb << 3) + t) << 6) + ((kq << 4) | s_)) * 8 + j] = (_Float16)W2[idx];
    }
    if (tid < 128) {
        sB[tid] = bias1[tid]; sB[128 + tid] = gam1[tid]; sB[256 + tid] = bet1[tid];
        sB[384 + tid] = bias2[tid]; sB[512 + tid] = gam2[tid]; sB[640 + tid] = bet2[tid];
    }
    __syncthreads();

    const int w = tid >> 6, lane = tid & 63, quad = lane >> 4, s = lane & 15;
    _Float16* myM1 = &sM1[w * (16 * 136)];

    float b1c[8], g1c[8], be1c[8], b2c[8], g2c[8], be2c[8];
    #pragma unroll
    for (int t = 0; t < 8; t++) {
        int c = s * 8 + t;
        b1c[t] = sB[c]; g1c[t] = sB[128 + c]; be1c[t] = sB[256 + c];
        b2c[t] = sB[384 + c]; g2c[t] = sB[512 + c]; be2c[t] = sB[640 + c];
    }

    const int gw = blockIdx.x * 8 + w, nwaves = gridDim.x * 8;
    const int nwt = (N_NODES + 15) >> 4;
    for (int wt = gw; wt < nwt; wt += nwaves) {
        const int nbase = wt << 4;
        int n = nbase + s; if (n >= N_NODES) n = N_NODES - 1;

        // GEMM1: A = [h[n] | agg[n]] straight from global f32
        f32x4 acc[8];
        #pragma unroll
        for (int t = 0; t < 8; t++) { f32x4 z = {0.f, 0.f, 0.f, 0.f}; acc[t] = z; }
        #pragma unroll
        for (int kb = 0; kb < 8; kb++) {
            const float* rp = (kb < 4) ? (h + (size_t)n * 128 + kb * 32 + quad * 8)
                                       : (agg + (size_t)n * 128 + (kb - 4) * 32 + quad * 8);
            half8 af = pack8(*(const float4*)rp, *(const float4*)(rp + 4));
            #pragma unroll
            for (int t = 0; t < 8; t++) {
                half8 bf = *(const half8*)(&sW1[(((kb << 3) + t) * 64 + lane) * 8]);
                acc[t] = __builtin_amdgcn_mfma_f32_16x16x32_f16(af, bf, acc[t], 0, 0, 0);
            }
        }

        // epilogue 1: LN ; relu ; -> myM1
        #pragma unroll
        for (int r = 0; r < 4; r++) {
            float v[8], sum = 0.f, sq = 0.f;
            #pragma unroll
            for (int t = 0; t < 8; t++) {
                v[t] = acc[t][r] + b1c[t];
                sum += v[t]; sq += v[t] * v[t];
            }
            #pragma unroll
            for (int m = 1; m < 16; m <<= 1) {
                sum += __shfl_xor(sum, m, 64);
                sq  += __shfl_xor(sq, m, 64);
            }
            float mean = sum * (1.f / 128.f);
            float var = sq * (1.f / 128.f) - mean * mean;
            float rstd = rsqrtf(var + 1e-5f);
            half8 hv;
            #pragma unroll
            for (int t = 0; t < 8; t++) {
                float y = (v[t] - mean) * rstd * g1c[t] + be1c[t];
                hv[t] = (_Float16)fmaxf(y, 0.f);
            }
            *(half8*)(&myM1[(quad * 4 + r) * 136 + s * 8]) = hv;
        }

        // GEMM2
        f32x4 acc2[8];
        #pragma unroll
        for (int t = 0; t < 8; t++) { f32x4 z = {0.f, 0.f, 0.f, 0.f}; acc2[t] = z; }
        #pragma unroll
        for (int kb = 0; kb < 4; kb++) {
            half8 af = *(const half8*)(&myM1[s * 136 + kb * 32 + quad * 8]);
            #pragma unroll
            for (int t = 0; t < 8; t++) {
                half8 bf = *(const half8*)(&sW2[(((kb << 3) + t) * 64 + lane) * 8]);
                acc2[t] = __builtin_amdgcn_mfma_f32_16x16x32_f16(af, bf, acc2[t], 0, 0, 0);
            }
        }

        // epilogue 2: LN ; relu ; h += u
        #pragma unroll
        for (int r = 0; r < 4; r++) {
            int nn = nbase + quad * 4 + r;
            float v[8], sum = 0.f, sq = 0.f;
            #pragma unroll
            for (int t = 0; t < 8; t++) {
                v[t] = acc2[t][r] + b2c[t];
                sum += v[t]; sq += v[t] * v[t];
            }
            #pragma unroll
            for (int m = 1; m < 16; m <<= 1) {
                sum += __shfl_xor(sum, m, 64);
                sq  += __shfl_xor(sq, m, 64);
            }
            float mean = sum * (1.f / 128.f);
            float var = sq * (1.f / 128.f) - mean * mean;
            float rstd = rsqrtf(var + 1e-5f);
            if (nn < N_NODES) {
                float* hp = h + (size_t)nn * 128 + s * 8;
                float4 h0 = *(float4*)hp;
                float4 h1 = *(float4*)(hp + 4);
                float y[8];
                #pragma unroll
                for (int t = 0; t < 8; t++) {
                    float u = (v[t] - mean) * rstd * g2c[t] + be2c[t];
                    y[t] = fmaxf(u, 0.f);
                }
                h0.x += y[0]; h0.y += y[1]; h0.z += y[2]; h0.w += y[3];
                h1.x += y[4]; h1.y += y[5]; h1.z += y[6]; h1.w += y[7];
                *(float4*)hp = h0;
                *(float4*)(hp + 4) = h1;
            }
        }
    }
}

// ---------------- pool (parallel, segmented + atomics) ----------------
__global__ void pool_kernel(const float* __restrict__ h, const int* __restrict__ batch,
                            float* __restrict__ g) {
    const int CHUNK = 125;
    int blo = blockIdx.x * CHUNK;
    int bhi = blo + CHUNK; if (bhi > N_NODES) bhi = N_NODES;
    int j = threadIdx.x & 127;
    int half = threadIdx.x >> 7;
    float acc = 0.f; int cur = -1;
    for (int n = blo + half; n < bhi; n += 2) {
        int b = batch[n];
        if (b != cur) {
            if (cur >= 0) atomicAdd(&g[cur * 128 + j], acc);
            cur = b; acc = 0.f;
        }
        acc += h[(size_t)n * 128 + j];
    }
    if (cur >= 0) atomicAdd(&g[cur * 128 + j], acc);
}

// ---------------- pred ----------------
__global__ void pred_kernel(const float* __restrict__ g, const float* __restrict__ W1,
                            const float* __restrict__ b1, const float* __restrict__ W2,
                            const float* __restrict__ b2, float* __restrict__ out) {
    int b = blockIdx.x, j = threadIdx.x;
    float t = b1[j];
    for (int k = 0; k < 128; k++) t += g[b * 128 + k] * W1[k * 128 + j];
    t = fmaxf(t, 0.f);
    __shared__ float red[128];
    red[j] = t * W2[j];
    __syncthreads();
    for (int off = 64; off > 0; off >>= 1) {
        if (j < off) red[j] += red[j + off];
        __syncthreads();
    }
    if (j == 0) out[b] = red[0] + b2[0];
}

extern "C" void kernel_launch(void* const* d_in, const int* in_sizes, int n_in,
                              void* d_out, int out_size, void* d_ws, size_t ws_size,
                              hipStream_t stream) {
    const float* x      = (const float*)d_in[0];
    const float* pos    = (const float*)d_in[1];
    const int*   ei     = (const int*)d_in[2];
    const int*   batch  = (const int*)d_in[3];
    const float* emb_W  = (const float*)d_in[4];
    const float* emb_b  = (const float*)d_in[5];
    const float* msg_W1 = (const float*)d_in[6];
    const float* msg_b1 = (const float*)d_in[7];
    const float* msg_W2 = (const float*)d_in[8];
    const float* msg_b2 = (const float*)d_in[9];
    const float* upd_W1 = (const float*)d_in[10];
    const float* upd_b1 = (const float*)d_in[11];
    const float* upd_W2 = (const float*)d_in[12];
    const float* upd_b2 = (const float*)d_in[13];
    const float* msg_g1 = (const float*)d_in[14];
    const float* msg_be1= (const float*)d_in[15];
    const float* msg_g2 = (const float*)d_in[16];
    const float* msg_be2= (const float*)d_in[17];
    const float* upd_g1 = (const float*)d_in[18];
    const float* upd_be1= (const float*)d_in[19];
    const float* upd_g2 = (const float*)d_in[20];
    const float* upd_be2= (const float*)d_in[21];
    const float* pred_W1= (const float*)d_in[22];
    const float* pred_b1= (const float*)d_in[23];
    const float* pred_W2= (const float*)d_in[24];
    const float* pred_b2= (const float*)d_in[25];
    float* out = (float*)d_out;

    float* ws = (float*)d_ws;
    float*     h      = ws;                           // 3.2M floats
    _Float16*  U      = (_Float16*)(ws + 3200000);    // 3.2M halves
    _Float16*  S      = (_Float16*)(ws + 4800000);    // 3.2M halves
    float*     agg    = ws + 6400000;                 // 3.2M floats
    int*       rowptr = (int*)(ws + 19200000);        // 25,008
    int*       cursor = rowptr + 25008;               // 25,008 (doubles as cnt)
    int*       src_s  = cursor + 25008;               // 200,000
    int*       dst_s  = src_s + 200000;               // 200,000
    float*     dist_s = (float*)(dst_s + 200000);     // 200,000
    float*     g      = dist_s + 200000;              // 8,192

    hipMemsetAsync(cursor, 0, 25001 * sizeof(int), stream);
    hist_kernel<<<(N_EDGES + 255) / 256, 256, 0, stream>>>(ei, cursor);
    scan_kernel<<<1, 1024, 0, stream>>>(cursor, rowptr, cursor);
    scatter_kernel<<<(N_EDGES + 255) / 256, 256, 0, stream>>>(ei, pos, cursor, src_s, dst_s, dist_s);

    embed_kernel<<<4096, 256, 0, stream>>>(x, emb_W, emb_b, h);

    for (int l = 0; l < DEPTH; l++) {
        const float* W1l = msg_W1 + (size_t)l * 257 * 128;
        us_kernel<<<256, 512, 0, stream>>>(h, W1l, msg_b1 + l * 128, U, S);
        hipMemsetAsync(agg, 0, (size_t)N_NODES * 128 * sizeof(float), stream);
        edge_kernel<<<512, 256, 0, stream>>>(
            U, S, dist_s, src_s, dst_s,
            W1l + 256 * 128, msg_g1 + l * 128, msg_be1 + l * 128,
            msg_W2 + (size_t)l * 128 * 128, msg_b2 + l * 128, msg_g2 + l * 128, msg_be2 + l * 128,
            agg);
        upd_kernel<<<256, 512, 0, stream>>>(
            h, agg,
            upd_W1 + (size_t)l * 256 * 128, upd_b1 + l * 128, upd_g1 + l * 128, upd_be1 + l * 128,
            upd_W2 + (size_t)l * 128 * 128, upd_b2 + l * 128, upd_g2 + l * 128, upd_be2 + l * 128);
    }

    hipMemsetAsync(g, 0, N_GRAPHS * 128 * sizeof(float), stream);
    pool_kernel<<<200, 256, 0, stream>>>(h, batch, g);
    pred_kernel<<<64, 128, 0, stream>>>(g, pred_W1, pred_b1, pred_W2, pred_b2, out);
}

// Round 11
// 834.165 us; speedup vs baseline: 1.8181x; 1.1307x over previous
//
#include <hip/hip_runtime.h>
#include <hip/hip_bf16.h>

#define N_NODES 25000
#define N_EDGES 200000
#define N_GRAPHS 64
#define HID 128
#define DEPTH 5

typedef _Float16 half8 __attribute__((ext_vector_type(8)));
typedef _Float16 half2v __attribute__((ext_vector_type(2)));
typedef float f32x4 __attribute__((ext_vector_type(4)));

__device__ inline half8 pack8(float4 a, float4 b) {
    half8 r;
    r[0] = (_Float16)a.x; r[1] = (_Float16)a.y; r[2] = (_Float16)a.z; r[3] = (_Float16)a.w;
    r[4] = (_Float16)b.x; r[5] = (_Float16)b.y; r[6] = (_Float16)b.z; r[7] = (_Float16)b.w;
    return r;
}

// ---------------- embed ----------------
__global__ void embed_kernel(const float* __restrict__ x, const float* __restrict__ W,
                             const float* __restrict__ b, float* __restrict__ h) {
    for (int i = blockIdx.x * blockDim.x + threadIdx.x; i < N_NODES * HID;
         i += gridDim.x * blockDim.x) {
        int n = i >> 7, j = i & 127;
        float acc = b[j];
        #pragma unroll
        for (int k = 0; k < 16; k++) acc += x[n * 16 + k] * W[k * 128 + j];
        h[i] = acc;
    }
}

// ---------------- weight prep: f32 -> f16 arenas in EXACT LDS image layouts ----------------
__global__ void prep_kernel(const float* __restrict__ msg_W1, const float* __restrict__ msg_W2,
                            const float* __restrict__ upd_W1, const float* __restrict__ upd_W2,
                            _Float16* __restrict__ usW, _Float16* __restrict__ eW2,
                            _Float16* __restrict__ uW1, _Float16* __restrict__ uW2) {
    int i = blockIdx.x * blockDim.x + threadIdx.x;
    const int N_US = DEPTH * 32768, N_E2 = DEPTH * 16384, N_U1 = DEPTH * 32768, N_U2 = DEPTH * 16384;
    if (i < N_US) {
        // us: sW[(kb*16+tt)*512 + (kq*16+s)*8 + j] = (tt<8 ? W1[kk][s*8+tt] : W1[128+kk][s*8+(tt-8)])
        int l = i >> 15, r = i & 32767;
        int j = r & 7, low6 = (r >> 3) & 63, kq = (low6 >> 4) & 3, s_ = low6 & 15;
        int rest = r >> 9, tt = rest & 15, kb = rest >> 4;
        int kk = (kb << 5) | (kq << 3) | j;
        int uh = tt >> 3, t = tt & 7, cc = s_ * 8 + t;
        const float* W1 = msg_W1 + (size_t)l * 257 * 128;
        usW[i] = (_Float16)(uh ? W1[(128 + kk) * 128 + cc] : W1[kk * 128 + cc]);
        return;
    }
    i -= N_US;
    if (i < N_E2) {
        int l = i >> 14, r = i & 16383;
        int j = r & 7, low6 = (r >> 3) & 63, kq = (low6 >> 4) & 3, s_ = low6 & 15;
        int rest = r >> 9, t = rest & 7, kb = rest >> 3;
        int k = (kb << 5) | (kq << 3) | j, c = s_ * 8 + t;
        eW2[i] = (_Float16)msg_W2[(size_t)l * 16384 + k * 128 + c];
        return;
    }
    i -= N_E2;
    if (i < N_U1) {
        int l = i >> 15, r = i & 32767;
        int j = r & 7, low6 = (r >> 3) & 63, kq = (low6 >> 4) & 3, s_ = low6 & 15;
        int rest = r >> 9, t = rest & 7, kb = rest >> 3;   // kb 0..7
        int k = (kb << 5) | (kq << 3) | j, c = s_ * 8 + t;
        uW1[i] = (_Float16)upd_W1[(size_t)l * 32768 + k * 128 + c];
        return;
    }
    i -= N_U1;
    if (i < N_U2) {
        int l = i >> 14, r = i & 16383;
        int j = r & 7, low6 = (r >> 3) & 63, kq = (low6 >> 4) & 3, s_ = low6 & 15;
        int rest = r >> 9, t = rest & 7, kb = rest >> 3;
        int k = (kb << 5) | (kq << 3) | j, c = s_ * 8 + t;
        uW2[i] = (_Float16)upd_W2[(size_t)l * 16384 + k * 128 + c];
    }
}

// ---------------- CSR build ----------------
__global__ void hist_kernel(const int* __restrict__ ei, int* __restrict__ cnt) {
    int e = blockIdx.x * blockDim.x + threadIdx.x;
    if (e < N_EDGES) atomicAdd(&cnt[ei[N_EDGES + e]], 1);
}

__global__ __launch_bounds__(1024)
void scan_kernel(const int* cnt, int* rowptr, int* cursor) {   // cnt may alias cursor
    __shared__ int swsum[16];
    __shared__ int stot;
    const int tid = threadIdx.x, wave = tid >> 6, lane = tid & 63;
    int carry = 0;
    for (int base = 0; base < N_NODES; base += 1024) {
        int i = base + tid;
        int v0 = (i < N_NODES) ? cnt[i] : 0;
        int v = v0;
        #pragma unroll
        for (int d = 1; d < 64; d <<= 1) {
            int t = __shfl_up(v, d, 64);
            if (lane >= d) v += t;
        }
        if (lane == 63) swsum[wave] = v;
        __syncthreads();
        if (wave == 0) {
            int sv = (lane < 16) ? swsum[lane] : 0;
            int si = sv;
            #pragma unroll
            for (int d = 1; d < 16; d <<= 1) {
                int t = __shfl_up(si, d, 64);
                if (lane >= d) si += t;
            }
            if (lane < 16) swsum[lane] = si - sv;
            if (lane == 15) stot = si;
        }
        __syncthreads();
        int excl = v - v0 + swsum[wave] + carry;
        if (i < N_NODES) { rowptr[i] = excl; cursor[i] = excl; }
        carry += stot;
        __syncthreads();
    }
    if (tid == 0) rowptr[N_NODES] = carry;
}

__global__ void scatter_kernel(const int* __restrict__ ei, const float* __restrict__ pos,
                               int* __restrict__ cursor, int* __restrict__ src_s,
                               int* __restrict__ dst_s, float* __restrict__ dist_s) {
    int e = blockIdx.x * blockDim.x + threadIdx.x;
    if (e < N_EDGES) {
        int s = ei[e], d = ei[N_EDGES + e];
        int p = atomicAdd(&cursor[d], 1);
        src_s[p] = s; dst_s[p] = d;
        float dx = pos[d * 3 + 0] - pos[s * 3 + 0];
        float dy = pos[d * 3 + 1] - pos[s * 3 + 1];
        float dz = pos[d * 3 + 2] - pos[s * 3 + 2];
        dist_s[p] = sqrtf(dx * dx + dy * dy + dz * dz);
    }
}

// ---------------- US precompute (arena-staged f16 weights) ----------------
__global__ __launch_bounds__(512, 2)
void us_kernel(const float* __restrict__ h, const _Float16* __restrict__ Wf,
               const float* __restrict__ bias1,
               _Float16* __restrict__ U, _Float16* __restrict__ S) {
    __shared__ __attribute__((aligned(16))) _Float16 sW[32768];   // [kb(4)][tt(16)][lane(64)][j(8)]
    __shared__ float sB1[128];
    const int tid = threadIdx.x;
    {
        const half8* wsrc = (const half8*)Wf;
        half8* wdst = (half8*)sW;
        #pragma unroll
        for (int idx = tid; idx < 4096; idx += 512) wdst[idx] = wsrc[idx];
    }
    if (tid < 128) sB1[tid] = bias1[tid];
    __syncthreads();

    const int w = tid >> 6, lane = tid & 63, quad = lane >> 4, s = lane & 15;
    float b1c[8];
    #pragma unroll
    for (int t = 0; t < 8; t++) b1c[t] = sB1[s * 8 + t];

    const int gw = blockIdx.x * 8 + w, nwaves = gridDim.x * 8;
    const int nwt = (N_NODES + 15) >> 4;
    for (int wt = gw; wt < nwt; wt += nwaves) {
        const int nbase = wt << 4;
        int n = nbase + s; if (n >= N_NODES) n = N_NODES - 1;

        half8 af[4];
        #pragma unroll
        for (int kb = 0; kb < 4; kb++) {
            const float* rp = h + (size_t)n * 128 + kb * 32 + quad * 8;
            af[kb] = pack8(*(const float4*)rp, *(const float4*)(rp + 4));
        }

        #pragma unroll
        for (int uhalf = 0; uhalf < 2; uhalf++) {
            f32x4 acc[8];
            #pragma unroll
            for (int t = 0; t < 8; t++) { f32x4 z = {0.f, 0.f, 0.f, 0.f}; acc[t] = z; }
            #pragma unroll
            for (int kb = 0; kb < 4; kb++) {
                #pragma unroll
                for (int t = 0; t < 8; t++) {
                    half8 bf = *(const half8*)(&sW[((((kb << 4) + (uhalf * 8 + t)) << 6) + lane) * 8]);
                    acc[t] = __builtin_amdgcn_mfma_f32_16x16x32_f16(af[kb], bf, acc[t], 0, 0, 0);
                }
            }
            _Float16* dstbuf = uhalf ? S : U;
            #pragma unroll
            for (int r = 0; r < 4; r++) {
                int nn = nbase + quad * 4 + r;
                if (nn < N_NODES) {
                    half8 ov;
                    #pragma unroll
                    for (int t = 0; t < 8; t++)
                        ov[t] = (_Float16)(acc[t][r] + (uhalf ? 0.f : b1c[t]));
                    *(half8*)(&dstbuf[(size_t)nn * 128 + s * 8]) = ov;
                }
            }
        }
    }
}

// ---------------- edge kernel: MLP + run-segmented atomic scatter ----------------
__global__ __launch_bounds__(256, 2)
void edge_kernel(const _Float16* __restrict__ U, const _Float16* __restrict__ S,
                 const float* __restrict__ dist_s, const int* __restrict__ src_s,
                 const int* __restrict__ dst_s,
                 const float* __restrict__ w256, const float* __restrict__ gam1,
                 const float* __restrict__ bet1,
                 const _Float16* __restrict__ W2f, const float* __restrict__ bias2,
                 const float* __restrict__ gam2, const float* __restrict__ bet2,
                 float* __restrict__ agg) {
    __shared__ __attribute__((aligned(16))) _Float16 sW2[16384];  // [kb(4)][t(8)][lane(64)][j(8)]
    __shared__ _Float16 sM1[17408];    // 4 waves x [32 rows][136]
    __shared__ int   sDstA[4][34];
    __shared__ int   sSrcA[4][32];
    __shared__ float sDistA[4][32];
    __shared__ float sB[768];

    const int tid = threadIdx.x;
    {
        const half8* wsrc = (const half8*)W2f;
        half8* wdst = (half8*)sW2;
        #pragma unroll
        for (int idx = tid; idx < 2048; idx += 256) wdst[idx] = wsrc[idx];
    }
    if (tid < 128) {
        sB[tid] = w256[tid];
        sB[128 + tid] = gam1[tid]; sB[256 + tid] = bet1[tid];
        sB[384 + tid] = bias2[tid]; sB[512 + tid] = gam2[tid]; sB[640 + tid] = bet2[tid];
    }
    __syncthreads();

    const int w = tid >> 6, lane = tid & 63, quad = lane >> 4, s = lane & 15;
    _Float16* myM1 = &sM1[w * (32 * 136)];
    int*   sDst  = sDstA[w];
    int*   sSrc  = sSrcA[w];
    float* sDist = sDistA[w];

    float w256c[8], g1c[8], be1c[8], b2c[8], g2c[8], be2c[8];
    #pragma unroll
    for (int t = 0; t < 8; t++) {
        int c = s * 8 + t;
        w256c[t] = sB[c]; g1c[t] = sB[128 + c]; be1c[t] = sB[256 + c];
        b2c[t] = sB[384 + c]; g2c[t] = sB[512 + c]; be2c[t] = sB[640 + c];
    }

    const int gw = blockIdx.x * 4 + w, nwaves = gridDim.x * 4;
    const int ewt = N_EDGES >> 5;   // exact
    for (int wt = gw; wt < ewt; wt += nwaves) {
        const int ebase = wt << 5;

        // phase 0: stage indices/dists into per-wave LDS (one coalesced pass)
        if (lane <= 32) {
            int e = ebase + lane;
            sDst[lane] = (e < N_EDGES) ? dst_s[e] : -1;
        } else {
            sSrc[lane - 33] = src_s[ebase + lane - 33];   // rows 0..30
        }
        if (lane < 32) sDist[lane] = dist_s[ebase + lane];
        else if (lane == 32) sSrc[31] = src_s[ebase + 31];
        bool bnd = (lane < 32) && (sDst[lane] != sDst[lane + 1]);
        unsigned mask = (unsigned)(__ballot(bnd) & 0xffffffffull);
        mask |= 0x80000000u;   // always flush at tile end (runs spanning tiles)

        // phase A: gather U/S rows (16 outstanding 16B loads)
        float distA[8];
        half8 u8A[8], s8A[8];
        #pragma unroll
        for (int i = 0; i < 8; i++) {
            int row = (i >> 2) * 16 + quad * 4 + (i & 3);
            int d = sDst[row], si = sSrc[row];
            distA[i] = sDist[row];
            u8A[i] = *(const half8*)(&U[(size_t)d * 128 + s * 8]);
            s8A[i] = *(const half8*)(&S[(size_t)si * 128 + s * 8]);
        }

        // phase B: LN + relu -> myM1 (per-wave; in-order DS pipe, no barrier)
        #pragma unroll
        for (int i = 0; i < 8; i++) {
            float v[8], sum = 0.f, sq = 0.f;
            #pragma unroll
            for (int t = 0; t < 8; t++) {
                v[t] = (float)u8A[i][t] + (float)s8A[i][t] + distA[i] * w256c[t];
                sum += v[t]; sq += v[t] * v[t];
            }
            #pragma unroll
            for (int m = 1; m < 16; m <<= 1) {
                sum += __shfl_xor(sum, m, 64);
                sq  += __shfl_xor(sq, m, 64);
            }
            float mean = sum * (1.f / 128.f);
            float var = sq * (1.f / 128.f) - mean * mean;
            float rstd = rsqrtf(var + 1e-5f);
            half8 hv;
            #pragma unroll
            for (int t = 0; t < 8; t++) {
                float y = (v[t] - mean) * rstd * g1c[t] + be1c[t];
                hv[t] = (_Float16)fmaxf(y, 0.f);
            }
            *(half8*)(&myM1[((i >> 2) * 16 + quad * 4 + (i & 3)) * 136 + s * 8]) = hv;
        }

        // GEMM2
        f32x4 acc2[2][8];
        #pragma unroll
        for (int mt = 0; mt < 2; mt++)
            #pragma unroll
            for (int t = 0; t < 8; t++) { f32x4 z = {0.f, 0.f, 0.f, 0.f}; acc2[mt][t] = z; }
        #pragma unroll
        for (int kb = 0; kb < 4; kb++) {
            half8 af[2];
            #pragma unroll
            for (int mt = 0; mt < 2; mt++)
                af[mt] = *(const half8*)(&myM1[(mt * 16 + s) * 136 + kb * 32 + quad * 8]);
            #pragma unroll
            for (int t = 0; t < 8; t++) {
                half8 bf = *(const half8*)(&sW2[(((kb << 3) + t) * 64 + lane) * 8]);
                acc2[0][t] = __builtin_amdgcn_mfma_f32_16x16x32_f16(af[0], bf, acc2[0][t], 0, 0, 0);
                acc2[1][t] = __builtin_amdgcn_mfma_f32_16x16x32_f16(af[1], bf, acc2[1][t], 0, 0, 0);
            }
        }

        // epilogue 2: LN ; relu ; m2 rows -> myM1
        #pragma unroll
        for (int mt = 0; mt < 2; mt++) {
            #pragma unroll
            for (int r = 0; r < 4; r++) {
                float v[8], sum = 0.f, sq = 0.f;
                #pragma unroll
                for (int t = 0; t < 8; t++) {
                    v[t] = acc2[mt][t][r] + b2c[t];
                    sum += v[t]; sq += v[t] * v[t];
                }
                #pragma unroll
                for (int m = 1; m < 16; m <<= 1) {
                    sum += __shfl_xor(sum, m, 64);
                    sq  += __shfl_xor(sq, m, 64);
                }
                float mean = sum * (1.f / 128.f);
                float var = sq * (1.f / 128.f) - mean * mean;
                float rstd = rsqrtf(var + 1e-5f);
                half8 hv;
                #pragma unroll
                for (int t = 0; t < 8; t++) {
                    float y = (v[t] - mean) * rstd * g2c[t] + be2c[t];
                    hv[t] = (_Float16)fmaxf(y, 0.f);
                }
                *(half8*)(&myM1[(mt * 16 + quad * 4 + r) * 136 + s * 8]) = hv;
            }
        }

        // phase C: run-segmented reduction; lane owns cols {2*lane, 2*lane+1}
        {
            const int col2 = lane * 2;
            half2v acc; acc[0] = (_Float16)0.f; acc[1] = (_Float16)0.f;
            for (int row = 0; row < 32; row++) {
                half2v v = *(const half2v*)(&myM1[row * 136 + col2]);
                acc += v;
                if ((mask >> row) & 1u) {                 // wave-uniform
                    int d = sDst[row];                    // LDS broadcast
                    float a0 = (float)acc[0], a1 = (float)acc[1];
                    if (a0 != 0.f) atomicAdd(&agg[(size_t)d * 128 + col2], a0);
                    if (a1 != 0.f) atomicAdd(&agg[(size_t)d * 128 + col2 + 1], a1);
                    acc[0] = (_Float16)0.f; acc[1] = (_Float16)0.f;
                }
            }
        }
    }
}

// ---------------- upd: node-MLP + residual (arena-staged f16 weights) ----------------
__global__ __launch_bounds__(512, 1)
void upd_kernel(float* __restrict__ h, const float* __restrict__ agg,
                const _Float16* __restrict__ W1f, const float* __restrict__ bias1,
                const float* __restrict__ gam1, const float* __restrict__ bet1,
                const _Float16* __restrict__ W2f, const float* __restrict__ bias2,
                const float* __restrict__ gam2, const float* __restrict__ bet2) {
    __shared__ __attribute__((aligned(16))) _Float16 sW1[32768];
    __shared__ __attribute__((aligned(16))) _Float16 sW2[16384];
    __shared__ _Float16 sM1[17408];   // 8 waves x [16 rows][136]
    __shared__ float sB[768];

    const int tid = threadIdx.x;
    {
        const half8* w1src = (const half8*)W1f;
        half8* w1dst = (half8*)sW1;
        #pragma unroll
        for (int idx = tid; idx < 4096; idx += 512) w1dst[idx] = w1src[idx];
        const half8* w2src = (const half8*)W2f;
        half8* w2dst = (half8*)sW2;
        #pragma unroll
        for (int idx = tid; idx < 2048; idx += 512) w2dst[idx] = w2src[idx];
    }
    if (tid < 128) {
        sB[tid] = bias1[tid]; sB[128 + tid] = gam1[tid]; sB[256 + tid] = bet1[tid];
        sB[384 + tid] = bias2[tid]; sB[512 + tid] = gam2[tid]; sB[640 + tid] = bet2[tid];
    }
    __syncthreads();

    const int w = tid >> 6, lane = tid & 63, quad = lane >> 4, s = lane & 15;
    _Float16* myM1 = &sM1[w * (16 * 136)];

    float b1c[8], g1c[8], be1c[8], b2c[8], g2c[8], be2c[8];
    #pragma unroll
    for (int t = 0; t < 8; t++) {
        int c = s * 8 + t;
        b1c[t] = sB[c]; g1c[t] = sB[128 + c]; be1c[t] = sB[256 + c];
        b2c[t] = sB[384 + c]; g2c[t] = sB[512 + c]; be2c[t] = sB[640 + c];
    }

    const int gw = blockIdx.x * 8 + w, nwaves = gridDim.x * 8;
    const int nwt = (N_NODES + 15) >> 4;
    for (int wt = gw; wt < nwt; wt += nwaves) {
        const int nbase = wt << 4;
        int n = nbase + s; if (n >= N_NODES) n = N_NODES - 1;

        // GEMM1: A = [h[n] | agg[n]] straight from global f32
        f32x4 acc[8];
        #pragma unroll
        for (int t = 0; t < 8; t++) { f32x4 z = {0.f, 0.f, 0.f, 0.f}; acc[t] = z; }
        #pragma unroll
        for (int kb = 0; kb < 8; kb++) {
            const float* rp = (kb < 4) ? (h + (size_t)n * 128 + kb * 32 + quad * 8)
                                       : (agg + (size_t)n * 128 + (kb - 4) * 32 + quad * 8);
            half8 af = pack8(*(const float4*)rp, *(const float4*)(rp + 4));
            #pragma unroll
            for (int t = 0; t < 8; t++) {
                half8 bf = *(const half8*)(&sW1[(((kb << 3) + t) * 64 + lane) * 8]);
                acc[t] = __builtin_amdgcn_mfma_f32_16x16x32_f16(af, bf, acc[t], 0, 0, 0);
            }
        }

        // epilogue 1: LN ; relu ; -> myM1
        #pragma unroll
        for (int r = 0; r < 4; r++) {
            float v[8], sum = 0.f, sq = 0.f;
            #pragma unroll
            for (int t = 0; t < 8; t++) {
                v[t] = acc[t][r] + b1c[t];
                sum += v[t]; sq += v[t] * v[t];
            }
            #pragma unroll
            for (int m = 1; m < 16; m <<= 1) {
                sum += __shfl_xor(sum, m, 64);
                sq  += __shfl_xor(sq, m, 64);
            }
            float mean = sum * (1.f / 128.f);
            float var = sq * (1.f / 128.f) - mean * mean;
            float rstd = rsqrtf(var + 1e-5f);
            half8 hv;
            #pragma unroll
            for (int t = 0; t < 8; t++) {
                float y = (v[t] - mean) * rstd * g1c[t] + be1c[t];
                hv[t] = (_Float16)fmaxf(y, 0.f);
            }
            *(half8*)(&myM1[(quad * 4 + r) * 136 + s * 8]) = hv;
        }

        // GEMM2
        f32x4 acc2[8];
        #pragma unroll
        for (int t = 0; t < 8; t++) { f32x4 z = {0.f, 0.f, 0.f, 0.f}; acc2[t] = z; }
        #pragma unroll
        for (int kb = 0; kb < 4; kb++) {
            half8 af = *(const half8*)(&myM1[s * 136 + kb * 32 + quad * 8]);
            #pragma unroll
            for (int t = 0; t < 8; t++) {
                half8 bf = *(const half8*)(&sW2[(((kb << 3) + t) * 64 + lane) * 8]);
                acc2[t] = __builtin_amdgcn_mfma_f32_16x16x32_f16(af, bf, acc2[t], 0, 0, 0);
            }
        }

        // epilogue 2: LN ; relu ; h += u
        #pragma unroll
        for (int r = 0; r < 4; r++) {
            int nn = nbase + quad * 4 + r;
            float v[8], sum = 0.f, sq = 0.f;
            #pragma unroll
            for (int t = 0; t < 8; t++) {
                v[t] = acc2[t][r] + b2c[t];
                sum += v[t]; sq += v[t] * v[t];
            }
            #pragma unroll
            for (int m = 1; m < 16; m <<= 1) {
                sum += __shfl_xor(sum, m, 64);
                sq  += __shfl_xor(sq, m, 64);
            }
            float mean = sum * (1.f / 128.f);
            float var = sq * (1.f / 128.f) - mean * mean;
            float rstd = rsqrtf(var + 1e-5f);
            if (nn < N_NODES) {
                float* hp = h + (size_t)nn * 128 + s * 8;
                float4 h0 = *(float4*)hp;
                float4 h1 = *(float4*)(hp + 4);
                float y[8];
                #pragma unroll
                for (int t = 0; t < 8; t++) {
                    float u = (v[t] - mean) * rstd * g2c[t] + be2c[t];
                    y[t] = fmaxf(u, 0.f);
                }
                h0.x += y[0]; h0.y += y[1]; h0.z += y[2]; h0.w += y[3];
                h1.x += y[4]; h1.y += y[5]; h1.z += y[6]; h1.w += y[7];
                *(float4*)hp = h0;
                *(float4*)(hp + 4) = h1;
            }
        }
    }
}

// ---------------- pool (parallel, segmented + atomics) ----------------
__global__ void pool_kernel(const float* __restrict__ h, const int* __restrict__ batch,
                            float* __restrict__ g) {
    const int CHUNK = 125;
    int blo = blockIdx.x * CHUNK;
    int bhi = blo + CHUNK; if (bhi > N_NODES) bhi = N_NODES;
    int j = threadIdx.x & 127;
    int half = threadIdx.x >> 7;
    float acc = 0.f; int cur = -1;
    for (int n = blo + half; n < bhi; n += 2) {
        int b = batch[n];
        if (b != cur) {
            if (cur >= 0) atomicAdd(&g[cur * 128 + j], acc);
            cur = b; acc = 0.f;
        }
        acc += h[(size_t)n * 128 + j];
    }
    if (cur >= 0) atomicAdd(&g[cur * 128 + j], acc);
}

// ---------------- pred ----------------
__global__ void pred_kernel(const float* __restrict__ g, const float* __restrict__ W1,
                            const float* __restrict__ b1, const float* __restrict__ W2,
                            const float* __restrict__ b2, float* __restrict__ out) {
    int b = blockIdx.x, j = threadIdx.x;
    float t = b1[j];
    for (int k = 0; k < 128; k++) t += g[b * 128 + k] * W1[k * 128 + j];
    t = fmaxf(t, 0.f);
    __shared__ float red[128];
    red[j] = t * W2[j];
    __syncthreads();
    for (int off = 64; off > 0; off >>= 1) {
        if (j < off) red[j] += red[j + off];
        __syncthreads();
    }
    if (j == 0) out[b] = red[0] + b2[0];
}

extern "C" void kernel_launch(void* const* d_in, const int* in_sizes, int n_in,
                              void* d_out, int out_size, void* d_ws, size_t ws_size,
                              hipStream_t stream) {
    const float* x      = (const float*)d_in[0];
    const float* pos    = (const float*)d_in[1];
    const int*   ei     = (const int*)d_in[2];
    const int*   batch  = (const int*)d_in[3];
    const float* emb_W  = (const float*)d_in[4];
    const float* emb_b  = (const float*)d_in[5];
    const float* msg_W1 = (const float*)d_in[6];
    const float* msg_b1 = (const float*)d_in[7];
    const float* msg_W2 = (const float*)d_in[8];
    const float* msg_b2 = (const float*)d_in[9];
    const float* upd_W1 = (const float*)d_in[10];
    const float* upd_b1 = (const float*)d_in[11];
    const float* upd_W2 = (const float*)d_in[12];
    const float* upd_b2 = (const float*)d_in[13];
    const float* msg_g1 = (const float*)d_in[14];
    const float* msg_be1= (const float*)d_in[15];
    const float* msg_g2 = (const float*)d_in[16];
    const float* msg_be2= (const float*)d_in[17];
    const float* upd_g1 = (const float*)d_in[18];
    const float* upd_be1= (const float*)d_in[19];
    const float* upd_g2 = (const float*)d_in[20];
    const float* upd_be2= (const float*)d_in[21];
    const float* pred_W1= (const float*)d_in[22];
    const float* pred_b1= (const float*)d_in[23];
    const float* pred_W2= (const float*)d_in[24];
    const float* pred_b2= (const float*)d_in[25];
    float* out = (float*)d_out;

    float* ws = (float*)d_ws;
    float*     h      = ws;                           // 3.2M floats
    _Float16*  U      = (_Float16*)(ws + 3200000);    // 3.2M halves
    _Float16*  S      = (_Float16*)(ws + 4800000);    // 3.2M halves
    float*     agg    = ws + 6400000;                 // 3.2M floats
    _Float16*  usW    = (_Float16*)(ws + 9600000);    // 5 x 32768 halves
    _Float16*  eW2    = usW + DEPTH * 32768;          // 5 x 16384
    _Float16*  uW1    = eW2 + DEPTH * 16384;          // 5 x 32768
    _Float16*  uW2    = uW1 + DEPTH * 32768;          // 5 x 16384
    int*       rowptr = (int*)(ws + 19200000);        // 25,008
    int*       cursor = rowptr + 25008;               // 25,008 (doubles as cnt)
    int*       src_s  = cursor + 25008;               // 200,000
    int*       dst_s  = src_s + 200000;               // 200,000
    float*     dist_s = (float*)(dst_s + 200000);     // 200,000
    float*     g      = dist_s + 200000;              // 8,192

    hipMemsetAsync(cursor, 0, 25001 * sizeof(int), stream);
    hist_kernel<<<(N_EDGES + 255) / 256, 256, 0, stream>>>(ei, cursor);
    scan_kernel<<<1, 1024, 0, stream>>>(cursor, rowptr, cursor);
    scatter_kernel<<<(N_EDGES + 255) / 256, 256, 0, stream>>>(ei, pos, cursor, src_s, dst_s, dist_s);
    prep_kernel<<<1920, 256, 0, stream>>>(msg_W1, msg_W2, upd_W1, upd_W2, usW, eW2, uW1, uW2);

    embed_kernel<<<4096, 256, 0, stream>>>(x, emb_W, emb_b, h);

    for (int l = 0; l < DEPTH; l++) {
        const float* W1l = msg_W1 + (size_t)l * 257 * 128;
        us_kernel<<<256, 512, 0, stream>>>(h, usW + (size_t)l * 32768, msg_b1 + l * 128, U, S);
        hipMemsetAsync(agg, 0, (size_t)N_NODES * 128 * sizeof(float), stream);
        edge_kernel<<<512, 256, 0, stream>>>(
            U, S, dist_s, src_s, dst_s,
            W1l + 256 * 128, msg_g1 + l * 128, msg_be1 + l * 128,
            eW2 + (size_t)l * 16384, msg_b2 + l * 128, msg_g2 + l * 128, msg_be2 + l * 128,
            agg);
        upd_kernel<<<256, 512, 0, stream>>>(
            h, agg,
            uW1 + (size_t)l * 32768, upd_b1 + l * 128, upd_g1 + l * 128, upd_be1 + l * 128,
            uW2 + (size_t)l * 16384, upd_b2 + l * 128, upd_g2 + l * 128, upd_be2 + l * 128);
    }

    hipMemsetAsync(g, 0, N_GRAPHS * 128 * sizeof(float), stream);
    pool_kernel<<<200, 256, 0, stream>>>(h, batch, g);
    pred_kernel<<<64, 128, 0, stream>>>(g, pred_W1, pred_b1, pred_W2, pred_b2, out);
}